// Round 10
// baseline (282.985 us; speedup 1.0000x reference)
//
#include <hip/hip_runtime.h>

using f16 = _Float16;
using half8  = __attribute__((ext_vector_type(8))) f16;
using half4v = __attribute__((ext_vector_type(4))) f16;
using float4v = __attribute__((ext_vector_type(4))) float;

#define DEV static __device__ __forceinline__

constexpr int N = 2048, DIM = 1024, H = 16, DH = 64, F6 = 6144;
constexpr int LDSH = 136;       // f16 epilogue row stride (halves)
constexpr int TS = 128 * 128;   // packed tile elements
constexpr int NTILES = 136;     // triangular 128x128 tiles per head
constexpr int KD = 2048 * 64;   // D/C elements per T-slice per head

// FRAG-MAJOR PANEL LAYOUT: 64-row x 64-col panel stored so that the half8
// a lane (q,m) consumes for (ks,ni) sits at element offset
//   (ks*256 + q*64 + ni*16 + m) * 8
// -> B-frag loads are fully coalesced AND panels are linear-copyable into LDS
//    with global_load_lds. Applied to DC, sigb, kch, vcT.

DEV int PL(int i, int k) { return i * (i + 1) / 2 + k; }                  // lower, k<=i
DEV int PU(int a, int b) { return a * 16 - a * (a - 1) / 2 + (b - a); }   // upper, a<=b

template<int ROWS, int THREADS>
DEV void stage64(const f16* __restrict__ g, int strideHalves, f16* lds, int tid) {
#pragma unroll
  for (int q = 0; q < (ROWS * 8) / THREADS; ++q) {
    const int chunk = q * THREADS + tid;
    const int m = chunk >> 3, c = (chunk & 7) ^ (m & 7);
    const f16* gp = g + (size_t)m * strideHalves + c * 8;
    __builtin_amdgcn_global_load_lds(
        (const __attribute__((address_space(1))) unsigned int*)gp,
        (__attribute__((address_space(3))) unsigned int*)(lds + chunk * 8), 16, 0, 0);
  }
}

// ELEMS contiguous halves -> LDS, (ELEMS/8/THREADS) x 16B per thread
template<int ELEMS, int THREADS>
DEV void stage_panel(const f16* __restrict__ g, f16* lds, int tid) {
#pragma unroll
  for (int i = 0; i < ELEMS / 8 / THREADS; ++i) {
    const int chunk = i * THREADS + tid;
    __builtin_amdgcn_global_load_lds(
        (const __attribute__((address_space(1))) unsigned int*)(g + (size_t)chunk * 8),
        (__attribute__((address_space(3))) unsigned int*)(lds + chunk * 8), 16, 0, 0);
  }
}

DEV half8 rdfrag(const f16* T, int m, int ks, int q) {
  const int c = (ks * 4 + q) ^ (m & 7);
  return *(const half8*)(T + m * 64 + c * 8);
}

// store one element into frag layout (inverse of rdfrag addressing)
DEV void wfrag(f16* T, int row, int col, f16 v) {
  T[row * 64 + ((((col >> 3) ^ (row & 7)) << 3) | (col & 7))] = v;
}

DEV void gemm64(const f16* As, const f16* Bs, int wm, int wn, int l, float4v acc[4][4]) {
  const int q = l >> 4, mm = l & 15;
#pragma unroll
  for (int ks = 0; ks < 2; ++ks) {
    half8 af[4], bf[4];
#pragma unroll
    for (int mi = 0; mi < 4; ++mi) af[mi] = rdfrag(As, wm + mm + mi * 16, ks, q);
#pragma unroll
    for (int ni = 0; ni < 4; ++ni) bf[ni] = rdfrag(Bs, wn + mm + ni * 16, ks, q);
#pragma unroll
    for (int mi = 0; mi < 4; ++mi)
#pragma unroll
      for (int ni = 0; ni < 4; ++ni)
        acc[mi][ni] = __builtin_amdgcn_mfma_f32_16x16x32_f16(af[mi], bf[ni], acc[mi][ni], 0, 0, 0);
  }
}

// p in [0,136) -> (ti,tk), tk<=ti.
DEV void decode_pair(int p, int& ti, int& tk) {
  int t = (int)((sqrtf(8.f * p + 1.f) - 1.f) * 0.5f);
  while (t * (t + 1) / 2 > p) --t;
  while ((t + 1) * (t + 2) / 2 <= p) ++t;
  const int i2 = p - t * (t + 1) / 2;
  ti = (15 - t) + i2;
  tk = i2;
}

__global__ __launch_bounds__(256) void k_cast(const float* __restrict__ s, f16* __restrict__ d, int n4) {
  int i = blockIdx.x * 256 + threadIdx.x;
  if (i < n4) {
    float4 v = ((const float4*)s)[i];
    half4v h;
    h[0] = (f16)v.x; h[1] = (f16)v.y; h[2] = (f16)v.z; h[3] = (f16)v.w;
    ((half4v*)d)[i] = h;
  }
}

// qkvs = x @ w_qkv^T; per-head scatter. vu additionally stored transposed (vuT[h][d][n]).
// kch and vcT are written in FRAG-MAJOR panel layout (consumed only by k_favs B-frags).
__global__ __launch_bounds__(256) void k_qkv(const f16* __restrict__ xh, const f16* __restrict__ wh,
                                             f16* __restrict__ quh, f16* __restrict__ kuh,
                                             f16* __restrict__ vuh, f16* __restrict__ qch,
                                             f16* __restrict__ kch, f16* __restrict__ vcT,
                                             f16* __restrict__ vuT) {
  __shared__ __align__(16) f16 lds[128 * LDSH];
  f16* As = lds; f16* Bs = lds + 128 * 64;
  const int tid = threadIdx.x, w = tid >> 6, l = tid & 63;
  const int tm = blockIdx.x * 128, tf = blockIdx.y * 128;
  const int wm = (w >> 1) * 64, wn = (w & 1) * 64;
  float4v acc[4][4] = {};
  for (int k0 = 0; k0 < DIM; k0 += 64) {
    stage64<128, 256>(xh + (size_t)tm * DIM + k0, DIM, As, tid);
    stage64<128, 256>(wh + (size_t)tf * DIM + k0, DIM, Bs, tid);
    __syncthreads();
    gemm64(As, Bs, wm, wn, l, acc);
    __syncthreads();
  }
  const int rbase = (l >> 4) * 4, cidx = l & 15;
  const int t = tf >> 10;
  const float sc = (t == 0 || t == 3) ? 0.125f : 1.f;
  if (t == 5 || t == 2) {
#pragma unroll
    for (int mi = 0; mi < 4; ++mi)
#pragma unroll
      for (int ni = 0; ni < 4; ++ni) {
        const int f = tf + wn + ni * 16 + cidx;
        const int h = (f & 1023) >> 6, d = f & 63;
        const int n = tm + wm + mi * 16 + rbase;
        half4v p;
#pragma unroll
        for (int r = 0; r < 4; ++r) p[r] = (f16)acc[mi][ni][r];
        if (t == 5) {
          // vcT frag panel: rows=d, cols=n; panel = n/64
          const int ks2 = (n & 63) >> 5, q2 = (n >> 3) & 3;
          const int inner = ks2 * 256 + q2 * 64 + (d >> 4) * 16 + (d & 15);
          *(half4v*)(vcT + (size_t)h * DH * N + (size_t)(n >> 6) * 4096 +
                     (size_t)inner * 8 + (n & 7)) = p;
        } else {
          *(half4v*)(vuT + ((size_t)h * DH + d) * N + n) = p;
        }
      }
  }
  if (t != 5) {
#pragma unroll
    for (int mi = 0; mi < 4; ++mi)
#pragma unroll
      for (int ni = 0; ni < 4; ++ni)
#pragma unroll
        for (int r = 0; r < 4; ++r)
          lds[(wm + mi * 16 + rbase + r) * LDSH + wn + ni * 16 + cidx] = (f16)(acc[mi][ni][r] * sc);
    __syncthreads();
    const int hb = (tf & 1023) >> 6;
    if (t == 4) {
      // kch frag panels: rows=k(seq), cols=d; contiguous dst, ~conflict-free lds src
#pragma unroll
      for (int qq = 0; qq < 8; ++qq) {
        const int idx = qq * 256 + tid;          // 2048 half8 = 2 heads x 1024
        const int hh = idx >> 10, f = idx & 1023;
        const int pl = f >> 9, inner = f & 511;
        const int m2 = inner & 15, ni2 = (inner >> 4) & 3, q2 = (inner >> 6) & 3, ks2 = inner >> 8;
        const int row = pl * 64 + ni2 * 16 + m2;
        const int col = hh * 64 + ks2 * 32 + q2 * 8;
        *(half8*)(kch + (size_t)(hb + hh) * N * DH + ((size_t)(tm >> 6) + pl) * 4096 +
                  (size_t)inner * 8) = *(const half8*)(lds + row * LDSH + col);
      }
    } else {
      f16* dst = (t == 0) ? quh : (t == 1) ? kuh : (t == 2) ? vuh : qch;
#pragma unroll
      for (int q = 0; q < 8; ++q) {
        const int idx = q * 256 + tid, row = idx >> 4, c = idx & 15;
        const int h = hb + (c >> 3), d0 = (c & 7) * 8, n = tm + row;
        *(half8*)(dst + ((size_t)h * N + n) * DH + d0) = *(const half8*)(lds + row * LDSH + c * 8);
      }
    }
  }
}

// Per pair (a<=b): sig tile PU(a,b) = triu1(sigmoid(qu[a].ku[b]^T)), computed ONCE;
// fused D-contribution D^{(b)}[a-rows] = sigtile @ vu[b-block]; for a==b also the
// diagonal term1 tile tril(qc[a].vu[a]^T). Grid (Gr,136): blockIdx.x = head (XCD pin).
// sigb and DC are written in FRAG-MAJOR layout (contiguous dst half8 stores).
__global__ __launch_bounds__(256) void k_dsig(const f16* __restrict__ quh, const f16* __restrict__ kuh,
                                              const f16* __restrict__ qch, const f16* __restrict__ vuh,
                                              const f16* __restrict__ vuT,
                                              f16* __restrict__ sigb, f16* __restrict__ DC,
                                              f16* __restrict__ diagb, int h0) {
  __shared__ __align__(16) f16 L[32768];  // quA 8192 | kuB 8192 (reused vtB0/vtB1) | s1 8192 | s2 8192
  f16* quA = L; f16* kuB = L + 8192; f16* s1 = L + 16384; f16* s2 = L + 24576;
  int b, a;
  decode_pair(blockIdx.y, b, a);
  const int hl = blockIdx.x, h = h0 + hl;
  const int tid = threadIdx.x, w = tid >> 6, l = tid & 63;
  const int q = l >> 4, m = l & 15;
  const int wm = (w >> 1) * 64, wn = (w & 1) * 64;
  const size_t ho = (size_t)h * N * DH;

  stage64<128, 256>(quh + ho + (size_t)(a * 128) * DH, DH, quA, tid);
  stage64<128, 256>(kuh + ho + (size_t)(b * 128) * DH, DH, kuB, tid);
  __syncthreads();
  float4v acc[4][4] = {};
  gemm64(quA, kuB, wm, wn, l, acc);  // qu[a] . ku[b]^T
  __syncthreads();  // quA/kuB reads done
  stage64<64, 256>(vuT + (size_t)h * DH * N + b * 128, N, kuB, tid);
  stage64<64, 256>(vuT + (size_t)h * DH * N + b * 128 + 64, N, kuB + 4096, tid);
  // sigmoid + strict-upper mask -> swizzled A-frag panels s1/s2  (rcp, not div)
#pragma unroll
  for (int mi = 0; mi < 4; ++mi)
#pragma unroll
    for (int ni = 0; ni < 4; ++ni)
#pragma unroll
      for (int r = 0; r < 4; ++r) {
        const int row = wm + mi * 16 + q * 4 + r;   // k-local
        const int col = wn + ni * 16 + m;           // j-local
        const float x = acc[mi][ni][r];
        const f16 sv = (b * 128 + col > a * 128 + row)
                           ? (f16)__builtin_amdgcn_rcpf(1.f + __expf(-x)) : (f16)0.f;
        wfrag((col < 64) ? s1 : s2, row, col & 63, sv);
      }
  __syncthreads();  // panels visible; vtB staged
  {
    // frag-major store: dst = Sg + idx*8 (contiguous); src from swizzled s1/s2
    f16* Sg = sigb + ((size_t)hl * NTILES + PU(a, b)) * TS;
#pragma unroll
    for (int qq = 0; qq < 8; ++qq) {
      const int idx = qq * 256 + tid;            // 2048 half8 = 128x128/8
      const int hf = idx >> 10, inner = idx & 1023;
      const int m2 = inner & 15, ni2 = (inner >> 4) & 3, q2 = (inner >> 6) & 3, ks2 = inner >> 8;
      const int row = hf * 64 + ni2 * 16 + m2;
      const int c8 = ks2 * 4 + q2;               // col/8 in 0..15
      const f16* p = ((c8 >> 3) ? s2 : s1) + row * 64 + (((c8 & 7) ^ (row & 7)) << 3);
      *(half8*)(Sg + (size_t)idx * 8) = *(const half8*)p;
    }
  }
  float4v dacc[2][4] = {};
#pragma unroll
  for (int p = 0; p < 2; ++p)
#pragma unroll
    for (int ks = 0; ks < 2; ++ks) {
      half8 bf[4], af[2];
#pragma unroll
      for (int ni = 0; ni < 4; ++ni) bf[ni] = rdfrag(kuB + p * 4096, ni * 16 + m, ks, q);
#pragma unroll
      for (int mi = 0; mi < 2; ++mi) af[mi] = rdfrag(p ? s2 : s1, w * 32 + mi * 16 + m, ks, q);
#pragma unroll
      for (int mi = 0; mi < 2; ++mi)
#pragma unroll
        for (int ni = 0; ni < 4; ++ni)
          dacc[mi][ni] = __builtin_amdgcn_mfma_f32_16x16x32_f16(af[mi], bf[ni], dacc[mi][ni], 0, 0, 0);
    }
  __syncthreads();
  if (a == b) {
    stage64<128, 256>(qch + ho + (size_t)(a * 128) * DH, DH, quA, tid);
    stage64<128, 256>(vuh + ho + (size_t)(a * 128) * DH, DH, kuB, tid);
  }
  {
    f16* epsD = s1;
#pragma unroll
    for (int mi = 0; mi < 2; ++mi)
#pragma unroll
      for (int ni = 0; ni < 4; ++ni)
#pragma unroll
        for (int r = 0; r < 4; ++r)
          epsD[(w * 32 + mi * 16 + q * 4 + r) * 68 + ni * 16 + m] = (f16)dacc[mi][ni][r];
    __syncthreads();
    // frag-major store: dst = Dg + idx*8 (contiguous)
    f16* Dg = DC + ((size_t)hl * 16 + b) * KD + (size_t)a * 8192;
#pragma unroll
    for (int qq = 0; qq < 4; ++qq) {
      const int idx = qq * 256 + tid;            // 1024 half8 = 128x64/8
      const int pl = idx >> 9, inner = idx & 511;
      const int m2 = inner & 15, ni2 = (inner >> 4) & 3, q2 = (inner >> 6) & 3, ks2 = inner >> 8;
      const int row = pl * 64 + ni2 * 16 + m2;
      const int c = ks2 * 4 + q2;                // 0..7
      *(half8*)(Dg + (size_t)idx * 8) = *(const half8*)(epsD + row * 68 + c * 8);
    }
  }
  if (a == b) {
    float4v tacc[4][4] = {};
    gemm64(quA, kuB, wm, wn, l, tacc);  // qc[a] . vu[a]^T
    f16* Tg = diagb + ((size_t)hl * 16 + a) * TS;
#pragma unroll
    for (int mi = 0; mi < 4; ++mi)
#pragma unroll
      for (int ni = 0; ni < 4; ++ni)
#pragma unroll
        for (int r = 0; r < 4; ++r) {
          const int row = wm + mi * 16 + q * 4 + r, col = wn + ni * 16 + m;
          Tg[(size_t)row * 128 + col] = (col <= row) ? (f16)tacc[mi][ni][r] : (f16)0.f;
        }
  }
}

// In-place exclusive prefix over T: C^{(T)} = sum_{T'<T} D^{(T')}, f32 accumulate.
// Works unchanged on frag-major DC: the frag permutation is within 8KB panels
// (off low 12 bits); a = off>>13 (row/128) is invariant.
__global__ __launch_bounds__(256) void k_scan(f16* __restrict__ DC, int total) {
  const int idx = blockIdx.x * 256 + threadIdx.x;
  if (idx >= total) return;
  const int g = idx >> 17, off = idx & (KD - 1);
  const int a = off >> 13;
  f16* p = DC + (size_t)g * 16 * KD + off;
  float s = 0.f;
#pragma unroll
  for (int T = 0; T < 16; ++T) {
    const float v = (T >= a) ? (float)p[(size_t)T * KD] : 0.f;
    p[(size_t)T * KD] = (f16)s;
    s += v;
  }
}

// Fused scores + online-softmax + PV. Round-9 parity-split pipeline kept
// (82us: waves {0,1}=rows x EVEN jt, {2,3}=rows x ODD jt; one staged 32KB sig
// tile per period serves all 4 waves; C prefetched a period ahead; counted
// vmcnt(16); 2 blocks/CU). Round-10 deltas:
//  (1) BALANCED CO-RESIDENT PAIRING: y<32 -> mt=63-y, y>=32 -> mt=y-32.
//      CU c hosts y=c/8 and y=c/8+32 -> mt pair sums to 63 -> per-CU periods
//      ~17.75 const (was 24..10, a ~40% long-pole tail). Consecutive y keep
//      consecutive mt (same-ti blocks stay XCD-adjacent -> L2 locality kept;
//      round-3's regression came from stride-2 scattering, avoided here).
//  (2) exp2-DOMAIN softmax: scale s once by log2(e); v_exp_f32 is natively
//      2^x, so every exp call drops its hidden multiply.
//  (3) defer-max (T13, THR=8/ln2): skip the alpha-rescale (exp + 16 o-muls +
//      lrun mul) when the tile max doesn't exceed mrun+THR. P bounded by
//      2^11.54 ~ 2981, inside f16 range; accumulators f32.
__global__ __launch_bounds__(256) void k_favs(const f16* __restrict__ qch, const f16* __restrict__ kch,
                                              const f16* __restrict__ DC, const f16* __restrict__ sigb,
                                              const f16* __restrict__ diagb, const f16* __restrict__ vcT,
                                              f16* __restrict__ Oh, int h0) {
  // [ Sg period-buf0 16384 | Sg period-buf1 16384 | P: 4 x 1024 ]
  __shared__ __align__(16) f16 L[2 * 16384 + 4 * 1024];
  const int hl = blockIdx.x, h = h0 + hl;
  const int y = (int)blockIdx.y;
  const int mt = (y < 32) ? (63 - y) : (y - 32);  // CU-balanced pairing (sum=63)
  const int tid = threadIdx.x, w = tid >> 6, l = tid & 63;
  const int q = l >> 4, m = l & 15;
  const int d = w >> 1;                 // jt parity owned by this wave
  const int rw = w & 1;                 // row half owned by this wave
  const int ti = mt >> 2, r0 = mt * 32;
  const size_t ho = (size_t)h * N * DH;
  const f16* qc = qch + ho;
  const f16* kcb = kch + ho;                        // frag panels
  const f16* Cb = DC + ((size_t)hl * 16 + ti) * KD; // frag panels
  const f16* Td = diagb + ((size_t)hl * 16 + ti) * TS;
  const f16* Sgb = sigb + (size_t)hl * NTILES * TS; // frag panels
  const f16* V = vcT + (size_t)h * DH * N;          // frag panels
  f16* pw = L + 32768 + w * 1024;                   // per-wave P region [16][64]
  const int lo = q * 512 + m * 8;                   // per-lane frag offset (halves)
  constexpr float L2E = 1.44269504f;
  constexpr float THR2 = 11.5416f;                  // 8 * log2(e)

  // A-frags: this wave's 16 REAL rows (rr = rw*16 + m)
  const int rr = rw * 16 + m;
  half8 qcA[2], tdA[4];
  const int dr = (mt & 3) * 32 + rr;                // row within 128 diag tile
#pragma unroll
  for (int ks = 0; ks < 2; ++ks)
    qcA[ks] = *(const half8*)(qc + (size_t)(r0 + rr) * DH + ks * 32 + q * 8);
#pragma unroll
  for (int ks = 0; ks < 4; ++ks)
    tdA[ks] = *(const half8*)(Td + (size_t)dr * 128 + ks * 32 + q * 8);

  float4v o[4] = {};
  float mrun[4], lrun[4];
#pragma unroll
  for (int r = 0; r < 4; ++r) { mrun[r] = -1e30f; lrun[r] = 0.f; }

  const int jtmax = mt >> 1;
  const int np = jtmax / 2 + 1;   // periods; period p covers chunks 2p, 2p+1
  // prologue: stage period 0's sig tile; prefetch period 0's C chunk
  stage_panel<16384, 256>(Sgb + (size_t)PU(0, ti) * TS, L, tid);
  half8 cC[2][4];
  {
    int c0 = d; if (c0 > jtmax) c0 = 0;  // clamp (unused when wave idles)
    const f16* Cp = Cb + (size_t)c0 * 4096 + lo;
#pragma unroll
    for (int ks = 0; ks < 2; ++ks)
#pragma unroll
      for (int ni = 0; ni < 4; ++ni) cC[ks][ni] = *(const half8*)(Cp + ks * 2048 + ni * 128);
  }

  for (int p = 0; p < np; ++p) {
    // issue next period's staging + C-prefetch (clamped; uniform 16 in flight)
    const int pn = (p + 1 <= ti) ? (p + 1) : ti;
    stage_panel<16384, 256>(Sgb + (size_t)PU(pn, ti) * TS,
                            L + ((p + 1) & 1) * 16384, tid);
    half8 nC[2][4];
    {
      int c2 = 2 * (p + 1) + d; if (c2 > jtmax) c2 = 0;
      const f16* Cp = Cb + (size_t)c2 * 4096 + lo;
#pragma unroll
      for (int ks = 0; ks < 2; ++ks)
#pragma unroll
        for (int ni = 0; ni < 4; ++ni) nC[ks][ni] = *(const half8*)(Cp + ks * 2048 + ni * 128);
    }
    asm volatile("s_waitcnt vmcnt(16)" ::: "memory");  // period p's stage+prefetch done
    __builtin_amdgcn_s_barrier();
    __builtin_amdgcn_sched_barrier(0);

    const int c = 2 * p + d;            // this wave-pair's chunk
    if (c <= jtmax) {
      const f16* Sp = L + (p & 1) * 16384 + d * 8192 + lo;   // staged sig half
      const f16* Kp = kcb + (size_t)c * 4096 + lo;
      const f16* Vp = V + (size_t)c * 4096 + lo;
      // bK issued immediately (consumed in phase 3, ~600cy slack)
      half8 bK[2][4];
#pragma unroll
      for (int ks = 0; ks < 2; ++ks)
#pragma unroll
        for (int ni = 0; ni < 4; ++ni) bK[ks][ni] = *(const half8*)(Kp + ks * 2048 + ni * 128);
      float4v s[4] = {};
      // phase 1: qc . C^{(ti)}[k]^T  (K=64) — cC prefetched last period
#pragma unroll
      for (int ks = 0; ks < 2; ++ks)
#pragma unroll
        for (int ni = 0; ni < 4; ++ni)
          s[ni] = __builtin_amdgcn_mfma_f32_16x16x32_f16(qcA[ks], cC[ks][ni], s[ni], 0, 0, 0);
      // phase 2: + T1diag . sig^T  (K=128) from staged Sg half
#pragma unroll
      for (int ks = 0; ks < 4; ++ks) {
        half8 bf[4];
#pragma unroll
        for (int ni = 0; ni < 4; ++ni) bf[ni] = *(const half8*)(Sp + ks * 2048 + ni * 128);
#pragma unroll
        for (int ni = 0; ni < 4; ++ni)
          s[ni] = __builtin_amdgcn_mfma_f32_16x16x32_f16(tdA[ks], bf[ni], s[ni], 0, 0, 0);
      }
      // issue V loads early (consumed after the softmax VALU chain)
      half8 bV[2][4];
#pragma unroll
      for (int ks = 0; ks < 2; ++ks)
#pragma unroll
        for (int ni = 0; ni < 4; ++ni) bV[ks][ni] = *(const half8*)(Vp + ks * 2048 + ni * 128);
      // s := -silu(Su)  (rcp, not div)
#pragma unroll
      for (int ni = 0; ni < 4; ++ni)
#pragma unroll
        for (int r = 0; r < 4; ++r) {
          const float x = s[ni][r];
          s[ni][r] = -x * __builtin_amdgcn_rcpf(1.f + __expf(-x));
        }
      // phase 3: + Sc = qc . kc^T  (K=64)
#pragma unroll
      for (int ks = 0; ks < 2; ++ks)
#pragma unroll
        for (int ni = 0; ni < 4; ++ni)
          s[ni] = __builtin_amdgcn_mfma_f32_16x16x32_f16(qcA[ks], bK[ks][ni], s[ni], 0, 0, 0);
      // causal mask (the diagonal chunk only)
      if (c == jtmax) {
        const int k0 = c * 64;
#pragma unroll
        for (int ni = 0; ni < 4; ++ni) {
          const int col = k0 + ni * 16 + m;
#pragma unroll
          for (int r = 0; r < 4; ++r) {
            const int gr = r0 + rw * 16 + q * 4 + r;
            if (col > gr) s[ni][r] = -1e30f;
          }
        }
      }
      // scale to exp2 domain once (kills the hidden mul in every exp)
#pragma unroll
      for (int ni = 0; ni < 4; ++ni)
#pragma unroll
        for (int r = 0; r < 4; ++r) s[ni][r] *= L2E;
      // online softmax in exp2 domain with defer-max (T13)
      float ts[4];
#pragma unroll
      for (int r = 0; r < 4; ++r) {
        float tmx = fmaxf(fmaxf(s[0][r], s[1][r]), fmaxf(s[2][r], s[3][r]));
#pragma unroll
        for (int x = 1; x < 16; x <<= 1) tmx = fmaxf(tmx, __shfl_xor(tmx, x));
        if (tmx > mrun[r] + THR2) {   // rescale only when max truly grows
          const float al = __builtin_amdgcn_exp2f(mrun[r] - tmx);
          mrun[r] = tmx;
          lrun[r] *= al;
#pragma unroll
          for (int ni = 0; ni < 4; ++ni) o[ni][r] *= al;
        }
        ts[r] = 0.f;
      }
#pragma unroll
      for (int ni = 0; ni < 4; ++ni)
#pragma unroll
        for (int r = 0; r < 4; ++r) {
          const float pp = __builtin_amdgcn_exp2f(s[ni][r] - mrun[r]);
          wfrag(pw, q * 4 + r, ni * 16 + m, (f16)pp);
          ts[r] += pp;
        }
#pragma unroll
      for (int r = 0; r < 4; ++r) {
#pragma unroll
        for (int x = 1; x < 16; x <<= 1) ts[r] += __shfl_xor(ts[r], x);
        lrun[r] += ts[r];
      }
      // PV: O += P(A via per-wave LDS) . vc(bV preloaded)
#pragma unroll
      for (int ks = 0; ks < 2; ++ks) {
        half8 af = rdfrag(pw, m, ks, q);
#pragma unroll
        for (int ni = 0; ni < 4; ++ni)
          o[ni] = __builtin_amdgcn_mfma_f32_16x16x32_f16(af, bV[ks][ni], o[ni], 0, 0, 0);
      }
    }
    __builtin_amdgcn_sched_barrier(0);
    __builtin_amdgcn_s_barrier();   // all reads of buf[p&1] done before overwrite
    // rotate prefetched C into place
#pragma unroll
    for (int ks = 0; ks < 2; ++ks)
#pragma unroll
      for (int ni = 0; ni < 4; ++ni) cC[ks][ni] = nC[ks][ni];
  }

  // drain dangling (garbage) staging before aliasing buf0 as merge scratch
  asm volatile("s_waitcnt vmcnt(0)" ::: "memory");
  __builtin_amdgcn_s_barrier();

  // 2-way merge across parity pairs: wave w+2 publishes partials, wave w combines.
  float* OB = (float*)L;
  float* MB = (float*)L + 2 * 16 * 68;
  float* LB = MB + 2 * 16;
  if (d == 1) {
#pragma unroll
    for (int ni = 0; ni < 4; ++ni)
#pragma unroll
      for (int r = 0; r < 4; ++r)
        OB[(rw * 16 + q * 4 + r) * 68 + ni * 16 + m] = o[ni][r];
    if (m == 0)
#pragma unroll
      for (int r = 0; r < 4; ++r) {
        MB[rw * 16 + q * 4 + r] = mrun[r];
        LB[rw * 16 + q * 4 + r] = lrun[r];
      }
  }
  __syncthreads();
  if (d == 0) {
#pragma unroll
    for (int r = 0; r < 4; ++r) {
      const int row = q * 4 + r;
      const float m2 = MB[rw * 16 + row], l2 = LB[rw * 16 + row];
      const float ms = fmaxf(mrun[r], m2);
      const float e1 = __builtin_amdgcn_exp2f(mrun[r] - ms);
      const float e2 = __builtin_amdgcn_exp2f(m2 - ms);
      const float inv = __builtin_amdgcn_rcpf(lrun[r] * e1 + l2 * e2);
      const int gr = r0 + rw * 16 + row;
#pragma unroll
      for (int ni = 0; ni < 4; ++ni) {
        const float ov = o[ni][r] * e1 + OB[(rw * 16 + row) * 68 + ni * 16 + m] * e2;
        Oh[(size_t)gr * (H * DH) + h * DH + ni * 16 + m] = (f16)(ov * inv);
      }
    }
  }
}

// out = O @ w_out^T, fp32 result.
__global__ __launch_bounds__(256) void k_out(const f16* __restrict__ Oh, const f16* __restrict__ wo,
                                             float* __restrict__ out) {
  __shared__ __align__(16) f16 lds[128 * LDSH];
  f16* As = lds; f16* Bs = lds + 128 * 64;
  const int tid = threadIdx.x, w = tid >> 6, l = tid & 63;
  const int tm = blockIdx.x * 128, tn = blockIdx.y * 128;
  const int wm = (w >> 1) * 64, wn = (w & 1) * 64;
  float4v acc[4][4] = {};
  for (int k0 = 0; k0 < DIM; k0 += 64) {
    stage64<128, 256>(Oh + (size_t)tm * DIM + k0, DIM, As, tid);
    stage64<128, 256>(wo + (size_t)tn * DIM + k0, DIM, Bs, tid);
    __syncthreads();
    gemm64(As, Bs, wm, wn, l, acc);
    __syncthreads();
  }
  const int rbase = (l >> 4) * 4, cidx = l & 15;
#pragma unroll
  for (int mi = 0; mi < 4; ++mi)
#pragma unroll
    for (int ni = 0; ni < 4; ++ni)
#pragma unroll
      for (int r = 0; r < 4; ++r) {
        const int n = tm + wm + mi * 16 + rbase + r;
        const int dmo = tn + wn + ni * 16 + cidx;
        out[(size_t)n * DIM + dmo] = acc[mi][ni][r];
      }
}

extern "C" void kernel_launch(void* const* d_in, const int* in_sizes, int n_in,
                              void* d_out, int out_size, void* d_ws, size_t ws_size,
                              hipStream_t stream) {
  const float* x = (const float*)d_in[0];
  const float* wqkv = (const float*)d_in[1];
  const float* wout = (const float*)d_in[2];
  float* out = (float*)d_out;
  char* ws = (char*)d_ws;

  size_t off = 0;
  auto alloc = [&](size_t b) { size_t o = off; off += (b + 255) & ~(size_t)255; return o; };
  f16* xh  = (f16*)(ws + alloc((size_t)N * DIM * 2));
  f16* wqh = (f16*)(ws + alloc((size_t)F6 * DIM * 2));
  f16* woh = (f16*)(ws + alloc((size_t)DIM * H * DH * 2));
  f16* quh = (f16*)(ws + alloc((size_t)H * N * DH * 2));
  f16* kuh = (f16*)(ws + alloc((size_t)H * N * DH * 2));
  f16* vuh = (f16*)(ws + alloc((size_t)H * N * DH * 2));
  f16* qch = (f16*)(ws + alloc((size_t)H * N * DH * 2));
  f16* kch = (f16*)(ws + alloc((size_t)H * N * DH * 2));
  f16* vcT = (f16*)(ws + alloc((size_t)H * DH * N * 2));
  f16* vuT = (f16*)(ws + alloc((size_t)H * DH * N * 2));
  f16* Oh  = (f16*)(ws + alloc((size_t)N * H * DH * 2));
  const size_t persist = off;

  // per head: sig tiles + D/C + diag tiles (scob eliminated by k_favs fusion)
  const size_t per_head = ((size_t)NTILES * TS + (size_t)16 * KD + (size_t)16 * TS) * 2;
  int G = (ws_size > persist + 4096) ? (int)((ws_size - persist - 4096) / per_head) : 1;
  if (G < 1) G = 1;
  if (G > 16) G = 16;
  {  // normalize so rounds are evenly sized (prefer G=8 for head->XCD pinning)
    const int R = (H + G - 1) / G;
    G = (H + R - 1) / R;
  }
  f16* sigb  = (f16*)(ws + alloc((size_t)G * NTILES * TS * 2));
  f16* DC    = (f16*)(ws + alloc((size_t)G * 16 * KD * 2));
  f16* diagb = (f16*)(ws + alloc((size_t)G * 16 * TS * 2));

  k_cast<<<(N * DIM / 4 + 255) / 256, 256, 0, stream>>>(x, xh, N * DIM / 4);
  k_cast<<<(F6 * DIM / 4 + 255) / 256, 256, 0, stream>>>(wqkv, wqh, F6 * DIM / 4);
  k_cast<<<(DIM * H * DH / 4 + 255) / 256, 256, 0, stream>>>(wout, woh, DIM * H * DH / 4);

  k_qkv<<<dim3(N / 128, F6 / 128), 256, 0, stream>>>(xh, wqh, quh, kuh, vuh, qch, kch, vcT, vuT);

  for (int h0 = 0; h0 < H; h0 += G) {
    const int Gr = (H - h0 < G) ? (H - h0) : G;
    k_dsig<<<dim3(Gr, 136), 256, 0, stream>>>(quh, kuh, qch, vuh, vuT, sigb, DC, diagb, h0);
    k_scan<<<(Gr * KD + 255) / 256, 256, 0, stream>>>(DC, Gr * KD);
    k_favs<<<dim3(Gr, 64), 256, 0, stream>>>(qch, kch, DC, sigb, diagb, vcT, Oh, h0);
  }

  k_out<<<dim3(16, 8), 256, 0, stream>>>(Oh, woh, out);
}

// Round 11
// 280.881 us; speedup vs baseline: 1.0075x; 1.0075x over previous
//
#include <hip/hip_runtime.h>

using f16 = _Float16;
using half8  = __attribute__((ext_vector_type(8))) f16;
using half4v = __attribute__((ext_vector_type(4))) f16;
using float4v = __attribute__((ext_vector_type(4))) float;

#define DEV static __device__ __forceinline__

constexpr int N = 2048, DIM = 1024, H = 16, DH = 64, F6 = 6144;
constexpr int LDSH = 136;       // f16 epilogue row stride (halves)
constexpr int TS = 128 * 128;   // packed tile elements
constexpr int NTILES = 136;     // triangular 128x128 tiles per head
constexpr int KD = 2048 * 64;   // D/C elements per T-slice per head

// FRAG-MAJOR PANEL LAYOUT: 64-row x 64-col panel stored so that the half8
// a lane (q,m) consumes for (ks,ni) sits at element offset
//   (ks*256 + q*64 + ni*16 + m) * 8
// -> B-frag loads are fully coalesced AND panels are linear-copyable into LDS
//    with global_load_lds. Applied to DC, sigb, kch, vcT.

DEV int PL(int i, int k) { return i * (i + 1) / 2 + k; }                  // lower, k<=i
DEV int PU(int a, int b) { return a * 16 - a * (a - 1) / 2 + (b - a); }   // upper, a<=b

template<int ROWS, int THREADS>
DEV void stage64(const f16* __restrict__ g, int strideHalves, f16* lds, int tid) {
#pragma unroll
  for (int q = 0; q < (ROWS * 8) / THREADS; ++q) {
    const int chunk = q * THREADS + tid;
    const int m = chunk >> 3, c = (chunk & 7) ^ (m & 7);
    const f16* gp = g + (size_t)m * strideHalves + c * 8;
    __builtin_amdgcn_global_load_lds(
        (const __attribute__((address_space(1))) unsigned int*)gp,
        (__attribute__((address_space(3))) unsigned int*)(lds + chunk * 8), 16, 0, 0);
  }
}

// ELEMS contiguous halves -> LDS, (ELEMS/8/THREADS) x 16B per thread
template<int ELEMS, int THREADS>
DEV void stage_panel(const f16* __restrict__ g, f16* lds, int tid) {
#pragma unroll
  for (int i = 0; i < ELEMS / 8 / THREADS; ++i) {
    const int chunk = i * THREADS + tid;
    __builtin_amdgcn_global_load_lds(
        (const __attribute__((address_space(1))) unsigned int*)(g + (size_t)chunk * 8),
        (__attribute__((address_space(3))) unsigned int*)(lds + chunk * 8), 16, 0, 0);
  }
}

DEV half8 rdfrag(const f16* T, int m, int ks, int q) {
  const int c = (ks * 4 + q) ^ (m & 7);
  return *(const half8*)(T + m * 64 + c * 8);
}

// store one element into frag layout (inverse of rdfrag addressing)
DEV void wfrag(f16* T, int row, int col, f16 v) {
  T[row * 64 + ((((col >> 3) ^ (row & 7)) << 3) | (col & 7))] = v;
}

DEV void gemm64(const f16* As, const f16* Bs, int wm, int wn, int l, float4v acc[4][4]) {
  const int q = l >> 4, mm = l & 15;
#pragma unroll
  for (int ks = 0; ks < 2; ++ks) {
    half8 af[4], bf[4];
#pragma unroll
    for (int mi = 0; mi < 4; ++mi) af[mi] = rdfrag(As, wm + mm + mi * 16, ks, q);
#pragma unroll
    for (int ni = 0; ni < 4; ++ni) bf[ni] = rdfrag(Bs, wn + mm + ni * 16, ks, q);
#pragma unroll
    for (int mi = 0; mi < 4; ++mi)
#pragma unroll
      for (int ni = 0; ni < 4; ++ni)
        acc[mi][ni] = __builtin_amdgcn_mfma_f32_16x16x32_f16(af[mi], bf[ni], acc[mi][ni], 0, 0, 0);
  }
}

// p in [0,136) -> (ti,tk), tk<=ti.
DEV void decode_pair(int p, int& ti, int& tk) {
  int t = (int)((sqrtf(8.f * p + 1.f) - 1.f) * 0.5f);
  while (t * (t + 1) / 2 > p) --t;
  while ((t + 1) * (t + 2) / 2 <= p) ++t;
  const int i2 = p - t * (t + 1) / 2;
  ti = (15 - t) + i2;
  tk = i2;
}

__global__ __launch_bounds__(256) void k_cast(const float* __restrict__ s, f16* __restrict__ d, int n4) {
  int i = blockIdx.x * 256 + threadIdx.x;
  if (i < n4) {
    float4 v = ((const float4*)s)[i];
    half4v h;
    h[0] = (f16)v.x; h[1] = (f16)v.y; h[2] = (f16)v.z; h[3] = (f16)v.w;
    ((half4v*)d)[i] = h;
  }
}

// qkvs = x @ w_qkv^T; per-head scatter. vu additionally stored transposed (vuT[h][d][n]).
// kch and vcT are written in FRAG-MAJOR panel layout (consumed only by k_favs B-frags).
__global__ __launch_bounds__(256) void k_qkv(const f16* __restrict__ xh, const f16* __restrict__ wh,
                                             f16* __restrict__ quh, f16* __restrict__ kuh,
                                             f16* __restrict__ vuh, f16* __restrict__ qch,
                                             f16* __restrict__ kch, f16* __restrict__ vcT,
                                             f16* __restrict__ vuT) {
  __shared__ __align__(16) f16 lds[128 * LDSH];
  f16* As = lds; f16* Bs = lds + 128 * 64;
  const int tid = threadIdx.x, w = tid >> 6, l = tid & 63;
  const int tm = blockIdx.x * 128, tf = blockIdx.y * 128;
  const int wm = (w >> 1) * 64, wn = (w & 1) * 64;
  float4v acc[4][4] = {};
  for (int k0 = 0; k0 < DIM; k0 += 64) {
    stage64<128, 256>(xh + (size_t)tm * DIM + k0, DIM, As, tid);
    stage64<128, 256>(wh + (size_t)tf * DIM + k0, DIM, Bs, tid);
    __syncthreads();
    gemm64(As, Bs, wm, wn, l, acc);
    __syncthreads();
  }
  const int rbase = (l >> 4) * 4, cidx = l & 15;
  const int t = tf >> 10;
  const float sc = (t == 0 || t == 3) ? 0.125f : 1.f;
  if (t == 5 || t == 2) {
#pragma unroll
    for (int mi = 0; mi < 4; ++mi)
#pragma unroll
      for (int ni = 0; ni < 4; ++ni) {
        const int f = tf + wn + ni * 16 + cidx;
        const int h = (f & 1023) >> 6, d = f & 63;
        const int n = tm + wm + mi * 16 + rbase;
        half4v p;
#pragma unroll
        for (int r = 0; r < 4; ++r) p[r] = (f16)acc[mi][ni][r];
        if (t == 5) {
          // vcT frag panel: rows=d, cols=n; panel = n/64
          const int ks2 = (n & 63) >> 5, q2 = (n >> 3) & 3;
          const int inner = ks2 * 256 + q2 * 64 + (d >> 4) * 16 + (d & 15);
          *(half4v*)(vcT + (size_t)h * DH * N + (size_t)(n >> 6) * 4096 +
                     (size_t)inner * 8 + (n & 7)) = p;
        } else {
          *(half4v*)(vuT + ((size_t)h * DH + d) * N + n) = p;
        }
      }
  }
  if (t != 5) {
#pragma unroll
    for (int mi = 0; mi < 4; ++mi)
#pragma unroll
      for (int ni = 0; ni < 4; ++ni)
#pragma unroll
        for (int r = 0; r < 4; ++r)
          lds[(wm + mi * 16 + rbase + r) * LDSH + wn + ni * 16 + cidx] = (f16)(acc[mi][ni][r] * sc);
    __syncthreads();
    const int hb = (tf & 1023) >> 6;
    if (t == 4) {
      // kch frag panels: rows=k(seq), cols=d; contiguous dst, ~conflict-free lds src
#pragma unroll
      for (int qq = 0; qq < 8; ++qq) {
        const int idx = qq * 256 + tid;          // 2048 half8 = 2 heads x 1024
        const int hh = idx >> 10, f = idx & 1023;
        const int pl = f >> 9, inner = f & 511;
        const int m2 = inner & 15, ni2 = (inner >> 4) & 3, q2 = (inner >> 6) & 3, ks2 = inner >> 8;
        const int row = pl * 64 + ni2 * 16 + m2;
        const int col = hh * 64 + ks2 * 32 + q2 * 8;
        *(half8*)(kch + (size_t)(hb + hh) * N * DH + ((size_t)(tm >> 6) + pl) * 4096 +
                  (size_t)inner * 8) = *(const half8*)(lds + row * LDSH + col);
      }
    } else {
      f16* dst = (t == 0) ? quh : (t == 1) ? kuh : (t == 2) ? vuh : qch;
#pragma unroll
      for (int q = 0; q < 8; ++q) {
        const int idx = q * 256 + tid, row = idx >> 4, c = idx & 15;
        const int h = hb + (c >> 3), d0 = (c & 7) * 8, n = tm + row;
        *(half8*)(dst + ((size_t)h * N + n) * DH + d0) = *(const half8*)(lds + row * LDSH + c * 8);
      }
    }
  }
}

// Per pair (a<=b): sig tile PU(a,b) = triu1(sigmoid(qu[a].ku[b]^T)), computed ONCE;
// fused D-contribution D^{(b)}[a-rows] = sigtile @ vu[b-block]; for a==b also the
// diagonal term1 tile tril(qc[a].vu[a]^T). Grid (Gr,136): blockIdx.x = head (XCD pin).
// sigb and DC are written in FRAG-MAJOR layout (contiguous dst half8 stores).
__global__ __launch_bounds__(256) void k_dsig(const f16* __restrict__ quh, const f16* __restrict__ kuh,
                                              const f16* __restrict__ qch, const f16* __restrict__ vuh,
                                              const f16* __restrict__ vuT,
                                              f16* __restrict__ sigb, f16* __restrict__ DC,
                                              f16* __restrict__ diagb, int h0) {
  __shared__ __align__(16) f16 L[32768];  // quA 8192 | kuB 8192 (reused vtB0/vtB1) | s1 8192 | s2 8192
  f16* quA = L; f16* kuB = L + 8192; f16* s1 = L + 16384; f16* s2 = L + 24576;
  int b, a;
  decode_pair(blockIdx.y, b, a);
  const int hl = blockIdx.x, h = h0 + hl;
  const int tid = threadIdx.x, w = tid >> 6, l = tid & 63;
  const int q = l >> 4, m = l & 15;
  const int wm = (w >> 1) * 64, wn = (w & 1) * 64;
  const size_t ho = (size_t)h * N * DH;

  stage64<128, 256>(quh + ho + (size_t)(a * 128) * DH, DH, quA, tid);
  stage64<128, 256>(kuh + ho + (size_t)(b * 128) * DH, DH, kuB, tid);
  __syncthreads();
  float4v acc[4][4] = {};
  gemm64(quA, kuB, wm, wn, l, acc);  // qu[a] . ku[b]^T
  __syncthreads();  // quA/kuB reads done
  stage64<64, 256>(vuT + (size_t)h * DH * N + b * 128, N, kuB, tid);
  stage64<64, 256>(vuT + (size_t)h * DH * N + b * 128 + 64, N, kuB + 4096, tid);
  // sigmoid + strict-upper mask -> swizzled A-frag panels s1/s2  (rcp, not div)
#pragma unroll
  for (int mi = 0; mi < 4; ++mi)
#pragma unroll
    for (int ni = 0; ni < 4; ++ni)
#pragma unroll
      for (int r = 0; r < 4; ++r) {
        const int row = wm + mi * 16 + q * 4 + r;   // k-local
        const int col = wn + ni * 16 + m;           // j-local
        const float x = acc[mi][ni][r];
        const f16 sv = (b * 128 + col > a * 128 + row)
                           ? (f16)__builtin_amdgcn_rcpf(1.f + __expf(-x)) : (f16)0.f;
        wfrag((col < 64) ? s1 : s2, row, col & 63, sv);
      }
  __syncthreads();  // panels visible; vtB staged
  {
    // frag-major store: dst = Sg + idx*8 (contiguous); src from swizzled s1/s2
    f16* Sg = sigb + ((size_t)hl * NTILES + PU(a, b)) * TS;
#pragma unroll
    for (int qq = 0; qq < 8; ++qq) {
      const int idx = qq * 256 + tid;            // 2048 half8 = 128x128/8
      const int hf = idx >> 10, inner = idx & 1023;
      const int m2 = inner & 15, ni2 = (inner >> 4) & 3, q2 = (inner >> 6) & 3, ks2 = inner >> 8;
      const int row = hf * 64 + ni2 * 16 + m2;
      const int c8 = ks2 * 4 + q2;               // col/8 in 0..15
      const f16* p = ((c8 >> 3) ? s2 : s1) + row * 64 + (((c8 & 7) ^ (row & 7)) << 3);
      *(half8*)(Sg + (size_t)idx * 8) = *(const half8*)p;
    }
  }
  float4v dacc[2][4] = {};
#pragma unroll
  for (int p = 0; p < 2; ++p)
#pragma unroll
    for (int ks = 0; ks < 2; ++ks) {
      half8 bf[4], af[2];
#pragma unroll
      for (int ni = 0; ni < 4; ++ni) bf[ni] = rdfrag(kuB + p * 4096, ni * 16 + m, ks, q);
#pragma unroll
      for (int mi = 0; mi < 2; ++mi) af[mi] = rdfrag(p ? s2 : s1, w * 32 + mi * 16 + m, ks, q);
#pragma unroll
      for (int mi = 0; mi < 2; ++mi)
#pragma unroll
        for (int ni = 0; ni < 4; ++ni)
          dacc[mi][ni] = __builtin_amdgcn_mfma_f32_16x16x32_f16(af[mi], bf[ni], dacc[mi][ni], 0, 0, 0);
    }
  __syncthreads();
  if (a == b) {
    stage64<128, 256>(qch + ho + (size_t)(a * 128) * DH, DH, quA, tid);
    stage64<128, 256>(vuh + ho + (size_t)(a * 128) * DH, DH, kuB, tid);
  }
  {
    f16* epsD = s1;
#pragma unroll
    for (int mi = 0; mi < 2; ++mi)
#pragma unroll
      for (int ni = 0; ni < 4; ++ni)
#pragma unroll
        for (int r = 0; r < 4; ++r)
          epsD[(w * 32 + mi * 16 + q * 4 + r) * 68 + ni * 16 + m] = (f16)dacc[mi][ni][r];
    __syncthreads();
    // frag-major store: dst = Dg + idx*8 (contiguous)
    f16* Dg = DC + ((size_t)hl * 16 + b) * KD + (size_t)a * 8192;
#pragma unroll
    for (int qq = 0; qq < 4; ++qq) {
      const int idx = qq * 256 + tid;            // 1024 half8 = 128x64/8
      const int pl = idx >> 9, inner = idx & 511;
      const int m2 = inner & 15, ni2 = (inner >> 4) & 3, q2 = (inner >> 6) & 3, ks2 = inner >> 8;
      const int row = pl * 64 + ni2 * 16 + m2;
      const int c = ks2 * 4 + q2;                // 0..7
      *(half8*)(Dg + (size_t)idx * 8) = *(const half8*)(epsD + row * 68 + c * 8);
    }
  }
  if (a == b) {
    float4v tacc[4][4] = {};
    gemm64(quA, kuB, wm, wn, l, tacc);  // qc[a] . vu[a]^T
    f16* Tg = diagb + ((size_t)hl * 16 + a) * TS;
#pragma unroll
    for (int mi = 0; mi < 4; ++mi)
#pragma unroll
      for (int ni = 0; ni < 4; ++ni)
#pragma unroll
        for (int r = 0; r < 4; ++r) {
          const int row = wm + mi * 16 + q * 4 + r, col = wn + ni * 16 + m;
          Tg[(size_t)row * 128 + col] = (col <= row) ? (f16)tacc[mi][ni][r] : (f16)0.f;
        }
  }
}

// In-place exclusive prefix over T: C^{(T)} = sum_{T'<T} D^{(T')}, f32 accumulate.
__global__ __launch_bounds__(256) void k_scan(f16* __restrict__ DC, int total) {
  const int idx = blockIdx.x * 256 + threadIdx.x;
  if (idx >= total) return;
  const int g = idx >> 17, off = idx & (KD - 1);
  const int a = off >> 13;
  f16* p = DC + (size_t)g * 16 * KD + off;
  float s = 0.f;
#pragma unroll
  for (int T = 0; T < 16; ++T) {
    const float v = (T >= a) ? (float)p[(size_t)T * KD] : 0.f;
    p[(size_t)T * KD] = (f16)s;
    s += v;
  }
}

// Fused scores + online-softmax + PV. Round-9 parity-split pipeline (82us) with
// mapping REVERTED to longest-first and defer-max branch removed (exp2 kept).
// Round-11 structural delta: TILE SPLITTING. Grid (Gr, 128): mt = 63-(y>>1),
// half hf = y&1. Half A runs periods [0, ceil(np/2)), half B the rest -> every
// block is <=9 periods (was 16 long pole); 1024 blocks at 2-resident/CU form a
// dispatch queue -> LPT packing -> wall ~ (periods/CU)/2 ~ 10 vs 16. Halves
// read DISJOINT sig periods (no extra FETCH). Each block writes an f32 partial
// (O', m, l) to its slot; k_merge combines the two slots into Oh (no cross-block
// ordering assumptions).
__global__ __launch_bounds__(256) void k_favs(const f16* __restrict__ qch, const f16* __restrict__ kch,
                                              const f16* __restrict__ DC, const f16* __restrict__ sigb,
                                              const f16* __restrict__ diagb, const f16* __restrict__ vcT,
                                              float* __restrict__ Opart, float* __restrict__ mpart,
                                              float* __restrict__ lpart, int h0) {
  // [ Sg period-buf0 16384 | Sg period-buf1 16384 | P: 4 x 1024 ]
  __shared__ __align__(16) f16 L[2 * 16384 + 4 * 1024];
  const int hl = blockIdx.x, h = h0 + hl;
  const int y = (int)blockIdx.y;
  const int mt = 63 - (y >> 1);         // longest-first
  const int hf = y & 1;                 // period half owned by this block
  const int tid = threadIdx.x, w = tid >> 6, l = tid & 63;
  const int q = l >> 4, m = l & 15;
  const int d = w >> 1;                 // jt parity owned by this wave
  const int rw = w & 1;                 // row half owned by this wave
  const int ti = mt >> 2, r0 = mt * 32;
  const size_t ho = (size_t)h * N * DH;
  const f16* qc = qch + ho;
  const f16* kcb = kch + ho;                        // frag panels
  const f16* Cb = DC + ((size_t)hl * 16 + ti) * KD; // frag panels
  const f16* Td = diagb + ((size_t)hl * 16 + ti) * TS;
  const f16* Sgb = sigb + (size_t)hl * NTILES * TS; // frag panels
  const f16* V = vcT + (size_t)h * DH * N;          // frag panels
  f16* pw = L + 32768 + w * 1024;                   // per-wave P region [16][64]
  const int lo = q * 512 + m * 8;                   // per-lane frag offset (halves)
  constexpr float L2E = 1.44269504f;

  // A-frags: this wave's 16 REAL rows (rr = rw*16 + m)
  const int rr = rw * 16 + m;
  half8 qcA[2], tdA[4];
  const int dr = (mt & 3) * 32 + rr;                // row within 128 diag tile
#pragma unroll
  for (int ks = 0; ks < 2; ++ks)
    qcA[ks] = *(const half8*)(qc + (size_t)(r0 + rr) * DH + ks * 32 + q * 8);
#pragma unroll
  for (int ks = 0; ks < 4; ++ks)
    tdA[ks] = *(const half8*)(Td + (size_t)dr * 128 + ks * 32 + q * 8);

  float4v o[4] = {};
  float mrun[4], lrun[4];
#pragma unroll
  for (int r = 0; r < 4; ++r) { mrun[r] = -1e30f; lrun[r] = 0.f; }

  const int jtmax = mt >> 1;
  const int np = jtmax / 2 + 1;          // total periods for this tile
  const int p0 = hf ? (np + 1) / 2 : 0;  // this block's period sub-range
  const int p1 = hf ? np : (np + 1) / 2;

  // prologue: stage period p0's sig tile; prefetch chunk 2*p0+d of C (clamped)
  const int ps0 = (p0 <= ti) ? p0 : ti;
  stage_panel<16384, 256>(Sgb + (size_t)PU(ps0, ti) * TS, L + (p0 & 1) * 16384, tid);
  half8 cC[2][4];
  {
    int c0 = 2 * p0 + d; if (c0 > jtmax) c0 = 0;
    const f16* Cp = Cb + (size_t)c0 * 4096 + lo;
#pragma unroll
    for (int ks = 0; ks < 2; ++ks)
#pragma unroll
      for (int ni = 0; ni < 4; ++ni) cC[ks][ni] = *(const half8*)(Cp + ks * 2048 + ni * 128);
  }

  for (int p = p0; p < p1; ++p) {
    // issue next period's staging + C-prefetch (clamped; uniform 16 in flight)
    const int pn = (p + 1 <= ti) ? (p + 1) : ti;
    stage_panel<16384, 256>(Sgb + (size_t)PU(pn, ti) * TS,
                            L + ((p + 1) & 1) * 16384, tid);
    half8 nC[2][4];
    {
      int c2 = 2 * (p + 1) + d; if (c2 > jtmax) c2 = 0;
      const f16* Cp = Cb + (size_t)c2 * 4096 + lo;
#pragma unroll
      for (int ks = 0; ks < 2; ++ks)
#pragma unroll
        for (int ni = 0; ni < 4; ++ni) nC[ks][ni] = *(const half8*)(Cp + ks * 2048 + ni * 128);
    }
    asm volatile("s_waitcnt vmcnt(16)" ::: "memory");  // period p's stage+prefetch done
    __builtin_amdgcn_s_barrier();
    __builtin_amdgcn_sched_barrier(0);

    const int c = 2 * p + d;            // this wave-pair's chunk
    if (c <= jtmax) {
      const f16* Sp = L + (p & 1) * 16384 + d * 8192 + lo;   // staged sig half
      const f16* Kp = kcb + (size_t)c * 4096 + lo;
      const f16* Vp = V + (size_t)c * 4096 + lo;
      // bK issued immediately (consumed in phase 3, ~600cy slack)
      half8 bK[2][4];
#pragma unroll
      for (int ks = 0; ks < 2; ++ks)
#pragma unroll
        for (int ni = 0; ni < 4; ++ni) bK[ks][ni] = *(const half8*)(Kp + ks * 2048 + ni * 128);
      float4v s[4] = {};
      // phase 1: qc . C^{(ti)}[k]^T  (K=64) — cC prefetched last period
#pragma unroll
      for (int ks = 0; ks < 2; ++ks)
#pragma unroll
        for (int ni = 0; ni < 4; ++ni)
          s[ni] = __builtin_amdgcn_mfma_f32_16x16x32_f16(qcA[ks], cC[ks][ni], s[ni], 0, 0, 0);
      // phase 2: + T1diag . sig^T  (K=128) from staged Sg half
#pragma unroll
      for (int ks = 0; ks < 4; ++ks) {
        half8 bf[4];
#pragma unroll
        for (int ni = 0; ni < 4; ++ni) bf[ni] = *(const half8*)(Sp + ks * 2048 + ni * 128);
#pragma unroll
        for (int ni = 0; ni < 4; ++ni)
          s[ni] = __builtin_amdgcn_mfma_f32_16x16x32_f16(tdA[ks], bf[ni], s[ni], 0, 0, 0);
      }
      // issue V loads early (consumed after the softmax VALU chain)
      half8 bV[2][4];
#pragma unroll
      for (int ks = 0; ks < 2; ++ks)
#pragma unroll
        for (int ni = 0; ni < 4; ++ni) bV[ks][ni] = *(const half8*)(Vp + ks * 2048 + ni * 128);
      // s := -silu(Su)  (rcp, not div)
#pragma unroll
      for (int ni = 0; ni < 4; ++ni)
#pragma unroll
        for (int r = 0; r < 4; ++r) {
          const float x = s[ni][r];
          s[ni][r] = -x * __builtin_amdgcn_rcpf(1.f + __expf(-x));
        }
      // phase 3: + Sc = qc . kc^T  (K=64)
#pragma unroll
      for (int ks = 0; ks < 2; ++ks)
#pragma unroll
        for (int ni = 0; ni < 4; ++ni)
          s[ni] = __builtin_amdgcn_mfma_f32_16x16x32_f16(qcA[ks], bK[ks][ni], s[ni], 0, 0, 0);
      // causal mask (the diagonal chunk only)
      if (c == jtmax) {
        const int k0 = c * 64;
#pragma unroll
        for (int ni = 0; ni < 4; ++ni) {
          const int col = k0 + ni * 16 + m;
#pragma unroll
          for (int r = 0; r < 4; ++r) {
            const int gr = r0 + rw * 16 + q * 4 + r;
            if (col > gr) s[ni][r] = -1e30f;
          }
        }
      }
      // scale to exp2 domain once; unconditional online rescale (branch-free)
#pragma unroll
      for (int ni = 0; ni < 4; ++ni)
#pragma unroll
        for (int r = 0; r < 4; ++r) s[ni][r] *= L2E;
      float ts[4];
#pragma unroll
      for (int r = 0; r < 4; ++r) {
        float tmx = fmaxf(fmaxf(s[0][r], s[1][r]), fmaxf(s[2][r], s[3][r]));
#pragma unroll
        for (int x = 1; x < 16; x <<= 1) tmx = fmaxf(tmx, __shfl_xor(tmx, x));
        const float nm = fmaxf(mrun[r], tmx);
        const float al = __builtin_amdgcn_exp2f(mrun[r] - nm);
        mrun[r] = nm;
        lrun[r] *= al;
#pragma unroll
        for (int ni = 0; ni < 4; ++ni) o[ni][r] *= al;
        ts[r] = 0.f;
      }
#pragma unroll
      for (int ni = 0; ni < 4; ++ni)
#pragma unroll
        for (int r = 0; r < 4; ++r) {
          const float pp = __builtin_amdgcn_exp2f(s[ni][r] - mrun[r]);
          wfrag(pw, q * 4 + r, ni * 16 + m, (f16)pp);
          ts[r] += pp;
        }
#pragma unroll
      for (int r = 0; r < 4; ++r) {
#pragma unroll
        for (int x = 1; x < 16; x <<= 1) ts[r] += __shfl_xor(ts[r], x);
        lrun[r] += ts[r];
      }
      // PV: O += P(A via per-wave LDS) . vc(bV preloaded)
#pragma unroll
      for (int ks = 0; ks < 2; ++ks) {
        half8 af = rdfrag(pw, m, ks, q);
#pragma unroll
        for (int ni = 0; ni < 4; ++ni)
          o[ni] = __builtin_amdgcn_mfma_f32_16x16x32_f16(af, bV[ks][ni], o[ni], 0, 0, 0);
      }
    }
    __builtin_amdgcn_sched_barrier(0);
    __builtin_amdgcn_s_barrier();   // all reads of buf[p&1] done before overwrite
    // rotate prefetched C into place
#pragma unroll
    for (int ks = 0; ks < 2; ++ks)
#pragma unroll
      for (int ni = 0; ni < 4; ++ni) cC[ks][ni] = nC[ks][ni];
  }

  // drain dangling (garbage) staging before aliasing buf0 as merge scratch
  asm volatile("s_waitcnt vmcnt(0)" ::: "memory");
  __builtin_amdgcn_s_barrier();

  // 2-way parity merge, then write UNNORMALIZED partial (O', m, l) to slot hf.
  float* OB = (float*)L;
  float* MB = (float*)L + 2 * 16 * 68;
  float* LB = MB + 2 * 16;
  if (d == 1) {
#pragma unroll
    for (int ni = 0; ni < 4; ++ni)
#pragma unroll
      for (int r = 0; r < 4; ++r)
        OB[(rw * 16 + q * 4 + r) * 68 + ni * 16 + m] = o[ni][r];
    if (m == 0)
#pragma unroll
      for (int r = 0; r < 4; ++r) {
        MB[rw * 16 + q * 4 + r] = mrun[r];
        LB[rw * 16 + q * 4 + r] = lrun[r];
      }
  }
  __syncthreads();
  if (d == 0) {
    float* Op = Opart + (size_t)(hl * 2 + hf) * N * 64;
    float* Mp = mpart + (hl * 2 + hf) * N;
    float* Lp = lpart + (hl * 2 + hf) * N;
#pragma unroll
    for (int r = 0; r < 4; ++r) {
      const int row = q * 4 + r;
      const float m2 = MB[rw * 16 + row], l2 = LB[rw * 16 + row];
      const float ms = fmaxf(mrun[r], m2);
      const float e1 = __builtin_amdgcn_exp2f(mrun[r] - ms);
      const float e2 = __builtin_amdgcn_exp2f(m2 - ms);
      const int gr = r0 + rw * 16 + row;
      if (m == 0) { Mp[gr] = ms; Lp[gr] = lrun[r] * e1 + l2 * e2; }
#pragma unroll
      for (int ni = 0; ni < 4; ++ni)
        Op[(size_t)gr * 64 + ni * 16 + m] =
            o[ni][r] * e1 + OB[(rw * 16 + row) * 68 + ni * 16 + m] * e2;
    }
  }
}

// Combine the two column-half partials per (head,row) and write normalized Oh.
__global__ __launch_bounds__(256) void k_merge(const float* __restrict__ Opart,
                                               const float* __restrict__ mpart,
                                               const float* __restrict__ lpart,
                                               f16* __restrict__ Oh, int h0) {
  const int hl = blockIdx.x, h = h0 + hl;
  const float* O0 = Opart + (size_t)(hl * 2 + 0) * N * 64;
  const float* O1 = Opart + (size_t)(hl * 2 + 1) * N * 64;
#pragma unroll
  for (int it = 0; it < 2; ++it) {
    const int idx = (int)blockIdx.y * 512 + it * 256 + threadIdx.x;  // [0, 32768)
    const int row = idx >> 4, c4 = idx & 15;
    const float m0 = mpart[(hl * 2 + 0) * N + row], m1 = mpart[(hl * 2 + 1) * N + row];
    const float l0 = lpart[(hl * 2 + 0) * N + row], l1 = lpart[(hl * 2 + 1) * N + row];
    const float ms = fmaxf(m0, m1);
    const float e0 = __builtin_amdgcn_exp2f(m0 - ms);
    const float e1 = __builtin_amdgcn_exp2f(m1 - ms);
    const float inv = __builtin_amdgcn_rcpf(l0 * e0 + l1 * e1);
    const float4 a = ((const float4*)(O0 + (size_t)row * 64))[c4];
    const float4 b = ((const float4*)(O1 + (size_t)row * 64))[c4];
    half4v o4;
    o4[0] = (f16)((a.x * e0 + b.x * e1) * inv);
    o4[1] = (f16)((a.y * e0 + b.y * e1) * inv);
    o4[2] = (f16)((a.z * e0 + b.z * e1) * inv);
    o4[3] = (f16)((a.w * e0 + b.w * e1) * inv);
    *(half4v*)(Oh + (size_t)row * (H * DH) + h * DH + c4 * 4) = o4;
  }
}

// out = O @ w_out^T, fp32 result.
__global__ __launch_bounds__(256) void k_out(const f16* __restrict__ Oh, const f16* __restrict__ wo,
                                             float* __restrict__ out) {
  __shared__ __align__(16) f16 lds[128 * LDSH];
  f16* As = lds; f16* Bs = lds + 128 * 64;
  const int tid = threadIdx.x, w = tid >> 6, l = tid & 63;
  const int tm = blockIdx.x * 128, tn = blockIdx.y * 128;
  const int wm = (w >> 1) * 64, wn = (w & 1) * 64;
  float4v acc[4][4] = {};
  for (int k0 = 0; k0 < DIM; k0 += 64) {
    stage64<128, 256>(Oh + (size_t)tm * DIM + k0, DIM, As, tid);
    stage64<128, 256>(wo + (size_t)tn * DIM + k0, DIM, Bs, tid);
    __syncthreads();
    gemm64(As, Bs, wm, wn, l, acc);
    __syncthreads();
  }
  const int rbase = (l >> 4) * 4, cidx = l & 15;
#pragma unroll
  for (int mi = 0; mi < 4; ++mi)
#pragma unroll
    for (int ni = 0; ni < 4; ++ni)
#pragma unroll
      for (int r = 0; r < 4; ++r) {
        const int n = tm + wm + mi * 16 + rbase + r;
        const int dmo = tn + wn + ni * 16 + cidx;
        out[(size_t)n * DIM + dmo] = acc[mi][ni][r];
      }
}

extern "C" void kernel_launch(void* const* d_in, const int* in_sizes, int n_in,
                              void* d_out, int out_size, void* d_ws, size_t ws_size,
                              hipStream_t stream) {
  const float* x = (const float*)d_in[0];
  const float* wqkv = (const float*)d_in[1];
  const float* wout = (const float*)d_in[2];
  float* out = (float*)d_out;
  char* ws = (char*)d_ws;

  size_t off = 0;
  auto alloc = [&](size_t b) { size_t o = off; off += (b + 255) & ~(size_t)255; return o; };
  f16* xh  = (f16*)(ws + alloc((size_t)N * DIM * 2));
  f16* wqh = (f16*)(ws + alloc((size_t)F6 * DIM * 2));
  f16* woh = (f16*)(ws + alloc((size_t)DIM * H * DH * 2));
  f16* quh = (f16*)(ws + alloc((size_t)H * N * DH * 2));
  f16* kuh = (f16*)(ws + alloc((size_t)H * N * DH * 2));
  f16* vuh = (f16*)(ws + alloc((size_t)H * N * DH * 2));
  f16* qch = (f16*)(ws + alloc((size_t)H * N * DH * 2));
  f16* kch = (f16*)(ws + alloc((size_t)H * N * DH * 2));
  f16* vcT = (f16*)(ws + alloc((size_t)H * DH * N * 2));
  f16* vuT = (f16*)(ws + alloc((size_t)H * DH * N * 2));
  f16* Oh  = (f16*)(ws + alloc((size_t)N * H * DH * 2));
  const size_t persist = off;

  // per head: sig tiles + D/C + diag tiles + split partials (O f32 x2, m/l x2)
  const size_t per_head = ((size_t)NTILES * TS + (size_t)16 * KD + (size_t)16 * TS) * 2 +
                          (size_t)2 * N * 64 * 4 + (size_t)4 * N * 4;
  int G = (ws_size > persist + 4096) ? (int)((ws_size - persist - 4096) / per_head) : 1;
  if (G < 1) G = 1;
  if (G > 16) G = 16;
  {  // normalize so rounds are evenly sized (prefer G=8 for head->XCD pinning)
    const int R = (H + G - 1) / G;
    G = (H + R - 1) / R;
  }
  f16* sigb  = (f16*)(ws + alloc((size_t)G * NTILES * TS * 2));
  f16* DC    = (f16*)(ws + alloc((size_t)G * 16 * KD * 2));
  f16* diagb = (f16*)(ws + alloc((size_t)G * 16 * TS * 2));
  float* Opart = (float*)(ws + alloc((size_t)G * 2 * N * 64 * 4));
  float* mpart = (float*)(ws + alloc((size_t)G * 2 * N * 4));
  float* lpart = (float*)(ws + alloc((size_t)G * 2 * N * 4));

  k_cast<<<(N * DIM / 4 + 255) / 256, 256, 0, stream>>>(x, xh, N * DIM / 4);
  k_cast<<<(F6 * DIM / 4 + 255) / 256, 256, 0, stream>>>(wqkv, wqh, F6 * DIM / 4);
  k_cast<<<(DIM * H * DH / 4 + 255) / 256, 256, 0, stream>>>(wout, woh, DIM * H * DH / 4);

  k_qkv<<<dim3(N / 128, F6 / 128), 256, 0, stream>>>(xh, wqh, quh, kuh, vuh, qch, kch, vcT, vuT);

  for (int h0 = 0; h0 < H; h0 += G) {
    const int Gr = (H - h0 < G) ? (H - h0) : G;
    k_dsig<<<dim3(Gr, 136), 256, 0, stream>>>(quh, kuh, qch, vuh, vuT, sigb, DC, diagb, h0);
    k_scan<<<(Gr * KD + 255) / 256, 256, 0, stream>>>(DC, Gr * KD);
    k_favs<<<dim3(Gr, 128), 256, 0, stream>>>(qch, kch, DC, sigb, diagb, vcT,
                                              Opart, mpart, lpart, h0);
    k_merge<<<dim3(Gr, 64), 256, 0, stream>>>(Opart, mpart, lpart, Oh, h0);
  }

  k_out<<<dim3(16, 8), 256, 0, stream>>>(Oh, woh, out);
}

// Round 12
// 263.465 us; speedup vs baseline: 1.0741x; 1.0661x over previous
//
#include <hip/hip_runtime.h>

using f16 = _Float16;
using half8  = __attribute__((ext_vector_type(8))) f16;
using half4v = __attribute__((ext_vector_type(4))) f16;
using float4v = __attribute__((ext_vector_type(4))) float;

#define DEV static __device__ __forceinline__

constexpr int N = 2048, DIM = 1024, H = 16, DH = 64, F6 = 6144;
constexpr int LDSH = 136;       // f16 epilogue row stride (halves)
constexpr int TS = 128 * 128;   // packed tile elements
constexpr int NTILES = 136;     // triangular 128x128 tiles per head
constexpr int KD = 2048 * 64;   // D/C elements per T-slice per head

// FRAG-MAJOR PANEL LAYOUT: 64-row x 64-col panel stored so that the half8
// a lane (q,m) consumes for (ks,ni) sits at element offset
//   (ks*256 + q*64 + ni*16 + m) * 8
// -> B-frag loads are fully coalesced AND panels are linear-copyable into LDS
//    with global_load_lds. Applied to DC, sigb, kch, vcT.

DEV int PL(int i, int k) { return i * (i + 1) / 2 + k; }                  // lower, k<=i
DEV int PU(int a, int b) { return a * 16 - a * (a - 1) / 2 + (b - a); }   // upper, a<=b

template<int ROWS, int THREADS>
DEV void stage64(const f16* __restrict__ g, int strideHalves, f16* lds, int tid) {
#pragma unroll
  for (int q = 0; q < (ROWS * 8) / THREADS; ++q) {
    const int chunk = q * THREADS + tid;
    const int m = chunk >> 3, c = (chunk & 7) ^ (m & 7);
    const f16* gp = g + (size_t)m * strideHalves + c * 8;
    __builtin_amdgcn_global_load_lds(
        (const __attribute__((address_space(1))) unsigned int*)gp,
        (__attribute__((address_space(3))) unsigned int*)(lds + chunk * 8), 16, 0, 0);
  }
}

// ELEMS contiguous halves -> LDS, (ELEMS/8/THREADS) x 16B per thread
template<int ELEMS, int THREADS>
DEV void stage_panel(const f16* __restrict__ g, f16* lds, int tid) {
#pragma unroll
  for (int i = 0; i < ELEMS / 8 / THREADS; ++i) {
    const int chunk = i * THREADS + tid;
    __builtin_amdgcn_global_load_lds(
        (const __attribute__((address_space(1))) unsigned int*)(g + (size_t)chunk * 8),
        (__attribute__((address_space(3))) unsigned int*)(lds + chunk * 8), 16, 0, 0);
  }
}

DEV half8 rdfrag(const f16* T, int m, int ks, int q) {
  const int c = (ks * 4 + q) ^ (m & 7);
  return *(const half8*)(T + m * 64 + c * 8);
}

// store one element into frag layout (inverse of rdfrag addressing)
DEV void wfrag(f16* T, int row, int col, f16 v) {
  T[row * 64 + ((((col >> 3) ^ (row & 7)) << 3) | (col & 7))] = v;
}

DEV void gemm64(const f16* As, const f16* Bs, int wm, int wn, int l, float4v acc[4][4]) {
  const int q = l >> 4, mm = l & 15;
#pragma unroll
  for (int ks = 0; ks < 2; ++ks) {
    half8 af[4], bf[4];
#pragma unroll
    for (int mi = 0; mi < 4; ++mi) af[mi] = rdfrag(As, wm + mm + mi * 16, ks, q);
#pragma unroll
    for (int ni = 0; ni < 4; ++ni) bf[ni] = rdfrag(Bs, wn + mm + ni * 16, ks, q);
#pragma unroll
    for (int mi = 0; mi < 4; ++mi)
#pragma unroll
      for (int ni = 0; ni < 4; ++ni)
        acc[mi][ni] = __builtin_amdgcn_mfma_f32_16x16x32_f16(af[mi], bf[ni], acc[mi][ni], 0, 0, 0);
  }
}

// p in [0,136) -> (ti,tk), tk<=ti.
DEV void decode_pair(int p, int& ti, int& tk) {
  int t = (int)((sqrtf(8.f * p + 1.f) - 1.f) * 0.5f);
  while (t * (t + 1) / 2 > p) --t;
  while ((t + 1) * (t + 2) / 2 <= p) ++t;
  const int i2 = p - t * (t + 1) / 2;
  ti = (15 - t) + i2;
  tk = i2;
}

__global__ __launch_bounds__(256) void k_cast(const float* __restrict__ s, f16* __restrict__ d, int n4) {
  int i = blockIdx.x * 256 + threadIdx.x;
  if (i < n4) {
    float4 v = ((const float4*)s)[i];
    half4v h;
    h[0] = (f16)v.x; h[1] = (f16)v.y; h[2] = (f16)v.z; h[3] = (f16)v.w;
    ((half4v*)d)[i] = h;
  }
}

// qkvs = x @ w_qkv^T; per-head scatter. vu additionally stored transposed (vuT[h][d][n]).
// kch and vcT are written in FRAG-MAJOR panel layout (consumed only by k_favs B-frags).
__global__ __launch_bounds__(256) void k_qkv(const f16* __restrict__ xh, const f16* __restrict__ wh,
                                             f16* __restrict__ quh, f16* __restrict__ kuh,
                                             f16* __restrict__ vuh, f16* __restrict__ qch,
                                             f16* __restrict__ kch, f16* __restrict__ vcT,
                                             f16* __restrict__ vuT) {
  __shared__ __align__(16) f16 lds[128 * LDSH];
  f16* As = lds; f16* Bs = lds + 128 * 64;
  const int tid = threadIdx.x, w = tid >> 6, l = tid & 63;
  const int tm = blockIdx.x * 128, tf = blockIdx.y * 128;
  const int wm = (w >> 1) * 64, wn = (w & 1) * 64;
  float4v acc[4][4] = {};
  for (int k0 = 0; k0 < DIM; k0 += 64) {
    stage64<128, 256>(xh + (size_t)tm * DIM + k0, DIM, As, tid);
    stage64<128, 256>(wh + (size_t)tf * DIM + k0, DIM, Bs, tid);
    __syncthreads();
    gemm64(As, Bs, wm, wn, l, acc);
    __syncthreads();
  }
  const int rbase = (l >> 4) * 4, cidx = l & 15;
  const int t = tf >> 10;
  const float sc = (t == 0 || t == 3) ? 0.125f : 1.f;
  if (t == 5 || t == 2) {
#pragma unroll
    for (int mi = 0; mi < 4; ++mi)
#pragma unroll
      for (int ni = 0; ni < 4; ++ni) {
        const int f = tf + wn + ni * 16 + cidx;
        const int h = (f & 1023) >> 6, d = f & 63;
        const int n = tm + wm + mi * 16 + rbase;
        half4v p;
#pragma unroll
        for (int r = 0; r < 4; ++r) p[r] = (f16)acc[mi][ni][r];
        if (t == 5) {
          // vcT frag panel: rows=d, cols=n; panel = n/64
          const int ks2 = (n & 63) >> 5, q2 = (n >> 3) & 3;
          const int inner = ks2 * 256 + q2 * 64 + (d >> 4) * 16 + (d & 15);
          *(half4v*)(vcT + (size_t)h * DH * N + (size_t)(n >> 6) * 4096 +
                     (size_t)inner * 8 + (n & 7)) = p;
        } else {
          *(half4v*)(vuT + ((size_t)h * DH + d) * N + n) = p;
        }
      }
  }
  if (t != 5) {
#pragma unroll
    for (int mi = 0; mi < 4; ++mi)
#pragma unroll
      for (int ni = 0; ni < 4; ++ni)
#pragma unroll
        for (int r = 0; r < 4; ++r)
          lds[(wm + mi * 16 + rbase + r) * LDSH + wn + ni * 16 + cidx] = (f16)(acc[mi][ni][r] * sc);
    __syncthreads();
    const int hb = (tf & 1023) >> 6;
    if (t == 4) {
      // kch frag panels: rows=k(seq), cols=d; contiguous dst, ~conflict-free lds src
#pragma unroll
      for (int qq = 0; qq < 8; ++qq) {
        const int idx = qq * 256 + tid;          // 2048 half8 = 2 heads x 1024
        const int hh = idx >> 10, f = idx & 1023;
        const int pl = f >> 9, inner = f & 511;
        const int m2 = inner & 15, ni2 = (inner >> 4) & 3, q2 = (inner >> 6) & 3, ks2 = inner >> 8;
        const int row = pl * 64 + ni2 * 16 + m2;
        const int col = hh * 64 + ks2 * 32 + q2 * 8;
        *(half8*)(kch + (size_t)(hb + hh) * N * DH + ((size_t)(tm >> 6) + pl) * 4096 +
                  (size_t)inner * 8) = *(const half8*)(lds + row * LDSH + col);
      }
    } else {
      f16* dst = (t == 0) ? quh : (t == 1) ? kuh : (t == 2) ? vuh : qch;
#pragma unroll
      for (int q = 0; q < 8; ++q) {
        const int idx = q * 256 + tid, row = idx >> 4, c = idx & 15;
        const int h = hb + (c >> 3), d0 = (c & 7) * 8, n = tm + row;
        *(half8*)(dst + ((size_t)h * N + n) * DH + d0) = *(const half8*)(lds + row * LDSH + c * 8);
      }
    }
  }
}

// Per pair (a<=b): sig tile PU(a,b) = triu1(sigmoid(qu[a].ku[b]^T)), computed ONCE;
// fused D-contribution D^{(b)}[a-rows] = sigtile @ vu[b-block]; for a==b also the
// diagonal term1 tile tril(qc[a].vu[a]^T). Grid (Gr,136): blockIdx.x = head (XCD pin).
// sigb and DC are written in FRAG-MAJOR layout (contiguous dst half8 stores).
__global__ __launch_bounds__(256) void k_dsig(const f16* __restrict__ quh, const f16* __restrict__ kuh,
                                              const f16* __restrict__ qch, const f16* __restrict__ vuh,
                                              const f16* __restrict__ vuT,
                                              f16* __restrict__ sigb, f16* __restrict__ DC,
                                              f16* __restrict__ diagb, int h0) {
  __shared__ __align__(16) f16 L[32768];  // quA 8192 | kuB 8192 (reused vtB0/vtB1) | s1 8192 | s2 8192
  f16* quA = L; f16* kuB = L + 8192; f16* s1 = L + 16384; f16* s2 = L + 24576;
  int b, a;
  decode_pair(blockIdx.y, b, a);
  const int hl = blockIdx.x, h = h0 + hl;
  const int tid = threadIdx.x, w = tid >> 6, l = tid & 63;
  const int q = l >> 4, m = l & 15;
  const int wm = (w >> 1) * 64, wn = (w & 1) * 64;
  const size_t ho = (size_t)h * N * DH;

  stage64<128, 256>(quh + ho + (size_t)(a * 128) * DH, DH, quA, tid);
  stage64<128, 256>(kuh + ho + (size_t)(b * 128) * DH, DH, kuB, tid);
  __syncthreads();
  float4v acc[4][4] = {};
  gemm64(quA, kuB, wm, wn, l, acc);  // qu[a] . ku[b]^T
  __syncthreads();  // quA/kuB reads done
  stage64<64, 256>(vuT + (size_t)h * DH * N + b * 128, N, kuB, tid);
  stage64<64, 256>(vuT + (size_t)h * DH * N + b * 128 + 64, N, kuB + 4096, tid);
  // sigmoid + strict-upper mask -> swizzled A-frag panels s1/s2  (rcp, not div)
#pragma unroll
  for (int mi = 0; mi < 4; ++mi)
#pragma unroll
    for (int ni = 0; ni < 4; ++ni)
#pragma unroll
      for (int r = 0; r < 4; ++r) {
        const int row = wm + mi * 16 + q * 4 + r;   // k-local
        const int col = wn + ni * 16 + m;           // j-local
        const float x = acc[mi][ni][r];
        const f16 sv = (b * 128 + col > a * 128 + row)
                           ? (f16)__builtin_amdgcn_rcpf(1.f + __expf(-x)) : (f16)0.f;
        wfrag((col < 64) ? s1 : s2, row, col & 63, sv);
      }
  __syncthreads();  // panels visible; vtB staged
  {
    // frag-major store: dst = Sg + idx*8 (contiguous); src from swizzled s1/s2
    f16* Sg = sigb + ((size_t)hl * NTILES + PU(a, b)) * TS;
#pragma unroll
    for (int qq = 0; qq < 8; ++qq) {
      const int idx = qq * 256 + tid;            // 2048 half8 = 128x128/8
      const int hf = idx >> 10, inner = idx & 1023;
      const int m2 = inner & 15, ni2 = (inner >> 4) & 3, q2 = (inner >> 6) & 3, ks2 = inner >> 8;
      const int row = hf * 64 + ni2 * 16 + m2;
      const int c8 = ks2 * 4 + q2;               // col/8 in 0..15
      const f16* p = ((c8 >> 3) ? s2 : s1) + row * 64 + (((c8 & 7) ^ (row & 7)) << 3);
      *(half8*)(Sg + (size_t)idx * 8) = *(const half8*)p;
    }
  }
  float4v dacc[2][4] = {};
#pragma unroll
  for (int p = 0; p < 2; ++p)
#pragma unroll
    for (int ks = 0; ks < 2; ++ks) {
      half8 bf[4], af[2];
#pragma unroll
      for (int ni = 0; ni < 4; ++ni) bf[ni] = rdfrag(kuB + p * 4096, ni * 16 + m, ks, q);
#pragma unroll
      for (int mi = 0; mi < 2; ++mi) af[mi] = rdfrag(p ? s2 : s1, w * 32 + mi * 16 + m, ks, q);
#pragma unroll
      for (int mi = 0; mi < 2; ++mi)
#pragma unroll
        for (int ni = 0; ni < 4; ++ni)
          dacc[mi][ni] = __builtin_amdgcn_mfma_f32_16x16x32_f16(af[mi], bf[ni], dacc[mi][ni], 0, 0, 0);
    }
  __syncthreads();
  if (a == b) {
    stage64<128, 256>(qch + ho + (size_t)(a * 128) * DH, DH, quA, tid);
    stage64<128, 256>(vuh + ho + (size_t)(a * 128) * DH, DH, kuB, tid);
  }
  {
    f16* epsD = s1;
#pragma unroll
    for (int mi = 0; mi < 2; ++mi)
#pragma unroll
      for (int ni = 0; ni < 4; ++ni)
#pragma unroll
        for (int r = 0; r < 4; ++r)
          epsD[(w * 32 + mi * 16 + q * 4 + r) * 68 + ni * 16 + m] = (f16)dacc[mi][ni][r];
    __syncthreads();
    // frag-major store: dst = Dg + idx*8 (contiguous)
    f16* Dg = DC + ((size_t)hl * 16 + b) * KD + (size_t)a * 8192;
#pragma unroll
    for (int qq = 0; qq < 4; ++qq) {
      const int idx = qq * 256 + tid;            // 1024 half8 = 128x64/8
      const int pl = idx >> 9, inner = idx & 511;
      const int m2 = inner & 15, ni2 = (inner >> 4) & 3, q2 = (inner >> 6) & 3, ks2 = inner >> 8;
      const int row = pl * 64 + ni2 * 16 + m2;
      const int c = ks2 * 4 + q2;                // 0..7
      *(half8*)(Dg + (size_t)idx * 8) = *(const half8*)(epsD + row * 68 + c * 8);
    }
  }
  if (a == b) {
    float4v tacc[4][4] = {};
    gemm64(quA, kuB, wm, wn, l, tacc);  // qc[a] . vu[a]^T
    f16* Tg = diagb + ((size_t)hl * 16 + a) * TS;
#pragma unroll
    for (int mi = 0; mi < 4; ++mi)
#pragma unroll
      for (int ni = 0; ni < 4; ++ni)
#pragma unroll
        for (int r = 0; r < 4; ++r) {
          const int row = wm + mi * 16 + q * 4 + r, col = wn + ni * 16 + m;
          Tg[(size_t)row * 128 + col] = (col <= row) ? (f16)tacc[mi][ni][r] : (f16)0.f;
        }
  }
}

// In-place exclusive prefix over T: C^{(T)} = sum_{T'<T} D^{(T')}, f32 accumulate.
__global__ __launch_bounds__(256) void k_scan(f16* __restrict__ DC, int total) {
  const int idx = blockIdx.x * 256 + threadIdx.x;
  if (idx >= total) return;
  const int g = idx >> 17, off = idx & (KD - 1);
  const int a = off >> 13;
  f16* p = DC + (size_t)g * 16 * KD + off;
  float s = 0.f;
#pragma unroll
  for (int T = 0; T < 16; ++T) {
    const float v = (T >= a) ? (float)p[(size_t)T * KD] : 0.f;
    p[(size_t)T * KD] = (f16)s;
    s += v;
  }
}

// Fused scores + online-softmax + PV. ROUND-9 STRUCTURE RESTORED (best total:
// parity-split waves, one staged 32KB sig tile/period for all 4 waves, C
// register-prefetch one period ahead, counted vmcnt(16), direct Oh writeout,
// 2-way LDS parity merge; grid (Gr,64), no k_merge). Round-12 deltas on top:
//  (1) exp2-domain branch-free online softmax (proven r10/r11).
//  (2) ROW-SUMS VIA ONES-MFMA: sum_k P[row][k] = (P . 1)[row]. Reuse PV's
//      A-frag with a constant all-ones B-frag -> o5 accumulates exact f32 row
//      sums across chunks (rescaled by al like any O column). Deletes the
//      4-step shfl sum-reduction chain per r (16 serialized DS ops + adds per
//      chunk) for +2 MFMA/chunk (MfmaUtil ~10% -> free).
__global__ __launch_bounds__(256) void k_favs(const f16* __restrict__ qch, const f16* __restrict__ kch,
                                              const f16* __restrict__ DC, const f16* __restrict__ sigb,
                                              const f16* __restrict__ diagb, const f16* __restrict__ vcT,
                                              f16* __restrict__ Oh, int h0) {
  // [ Sg period-buf0 16384 | Sg period-buf1 16384 | P: 4 x 1024 ]
  __shared__ __align__(16) f16 L[2 * 16384 + 4 * 1024];
  const int hl = blockIdx.x, h = h0 + hl;
  const int mt = 63 - (int)blockIdx.y;  // longest-first
  const int tid = threadIdx.x, w = tid >> 6, l = tid & 63;
  const int q = l >> 4, m = l & 15;
  const int d = w >> 1;                 // jt parity owned by this wave
  const int rw = w & 1;                 // row half owned by this wave
  const int ti = mt >> 2, r0 = mt * 32;
  const size_t ho = (size_t)h * N * DH;
  const f16* qc = qch + ho;
  const f16* kcb = kch + ho;                        // frag panels
  const f16* Cb = DC + ((size_t)hl * 16 + ti) * KD; // frag panels
  const f16* Td = diagb + ((size_t)hl * 16 + ti) * TS;
  const f16* Sgb = sigb + (size_t)hl * NTILES * TS; // frag panels
  const f16* V = vcT + (size_t)h * DH * N;          // frag panels
  f16* pw = L + 32768 + w * 1024;                   // per-wave P region [16][64]
  const int lo = q * 512 + m * 8;                   // per-lane frag offset (halves)
  constexpr float L2E = 1.44269504f;

  // A-frags: this wave's 16 REAL rows (rr = rw*16 + m)
  const int rr = rw * 16 + m;
  half8 qcA[2], tdA[4];
  const int dr = (mt & 3) * 32 + rr;                // row within 128 diag tile
#pragma unroll
  for (int ks = 0; ks < 2; ++ks)
    qcA[ks] = *(const half8*)(qc + (size_t)(r0 + rr) * DH + ks * 32 + q * 8);
#pragma unroll
  for (int ks = 0; ks < 4; ++ks)
    tdA[ks] = *(const half8*)(Td + (size_t)dr * 128 + ks * 32 + q * 8);

  half8 ones;
#pragma unroll
  for (int e = 0; e < 8; ++e) ones[e] = (f16)1.f;

  float4v o[4] = {};
  float4v o5 = {};                       // row sums of P (lrun), via ones-MFMA
  float mrun[4];
#pragma unroll
  for (int r = 0; r < 4; ++r) mrun[r] = -1e30f;

  const int jtmax = mt >> 1;
  const int np = jtmax / 2 + 1;   // periods; period p covers chunks 2p, 2p+1
  // prologue: stage period 0's sig tile; prefetch period 0's C chunk
  stage_panel<16384, 256>(Sgb + (size_t)PU(0, ti) * TS, L, tid);
  half8 cC[2][4];
  {
    int c0 = d; if (c0 > jtmax) c0 = 0;  // clamp (unused when wave idles)
    const f16* Cp = Cb + (size_t)c0 * 4096 + lo;
#pragma unroll
    for (int ks = 0; ks < 2; ++ks)
#pragma unroll
      for (int ni = 0; ni < 4; ++ni) cC[ks][ni] = *(const half8*)(Cp + ks * 2048 + ni * 128);
  }

  for (int p = 0; p < np; ++p) {
    // issue next period's staging + C-prefetch (clamped; uniform 16 in flight)
    const int pn = (p + 1 <= ti) ? (p + 1) : ti;
    stage_panel<16384, 256>(Sgb + (size_t)PU(pn, ti) * TS,
                            L + ((p + 1) & 1) * 16384, tid);
    half8 nC[2][4];
    {
      int c2 = 2 * (p + 1) + d; if (c2 > jtmax) c2 = 0;
      const f16* Cp = Cb + (size_t)c2 * 4096 + lo;
#pragma unroll
      for (int ks = 0; ks < 2; ++ks)
#pragma unroll
        for (int ni = 0; ni < 4; ++ni) nC[ks][ni] = *(const half8*)(Cp + ks * 2048 + ni * 128);
    }
    asm volatile("s_waitcnt vmcnt(16)" ::: "memory");  // period p's stage+prefetch done
    __builtin_amdgcn_s_barrier();
    __builtin_amdgcn_sched_barrier(0);

    const int c = 2 * p + d;            // this wave-pair's chunk
    if (c <= jtmax) {
      const f16* Sp = L + (p & 1) * 16384 + d * 8192 + lo;   // staged sig half
      const f16* Kp = kcb + (size_t)c * 4096 + lo;
      const f16* Vp = V + (size_t)c * 4096 + lo;
      // bK issued immediately (consumed in phase 3, ~600cy slack)
      half8 bK[2][4];
#pragma unroll
      for (int ks = 0; ks < 2; ++ks)
#pragma unroll
        for (int ni = 0; ni < 4; ++ni) bK[ks][ni] = *(const half8*)(Kp + ks * 2048 + ni * 128);
      float4v s[4] = {};
      // phase 1: qc . C^{(ti)}[k]^T  (K=64) — cC prefetched last period
#pragma unroll
      for (int ks = 0; ks < 2; ++ks)
#pragma unroll
        for (int ni = 0; ni < 4; ++ni)
          s[ni] = __builtin_amdgcn_mfma_f32_16x16x32_f16(qcA[ks], cC[ks][ni], s[ni], 0, 0, 0);
      // phase 2: + T1diag . sig^T  (K=128) from staged Sg half
#pragma unroll
      for (int ks = 0; ks < 4; ++ks) {
        half8 bf[4];
#pragma unroll
        for (int ni = 0; ni < 4; ++ni) bf[ni] = *(const half8*)(Sp + ks * 2048 + ni * 128);
#pragma unroll
        for (int ni = 0; ni < 4; ++ni)
          s[ni] = __builtin_amdgcn_mfma_f32_16x16x32_f16(tdA[ks], bf[ni], s[ni], 0, 0, 0);
      }
      // issue V loads early (consumed after the softmax VALU chain)
      half8 bV[2][4];
#pragma unroll
      for (int ks = 0; ks < 2; ++ks)
#pragma unroll
        for (int ni = 0; ni < 4; ++ni) bV[ks][ni] = *(const half8*)(Vp + ks * 2048 + ni * 128);
      // s := -silu(Su)  (rcp, not div)
#pragma unroll
      for (int ni = 0; ni < 4; ++ni)
#pragma unroll
        for (int r = 0; r < 4; ++r) {
          const float x = s[ni][r];
          s[ni][r] = -x * __builtin_amdgcn_rcpf(1.f + __expf(-x));
        }
      // phase 3: + Sc = qc . kc^T  (K=64)
#pragma unroll
      for (int ks = 0; ks < 2; ++ks)
#pragma unroll
        for (int ni = 0; ni < 4; ++ni)
          s[ni] = __builtin_amdgcn_mfma_f32_16x16x32_f16(qcA[ks], bK[ks][ni], s[ni], 0, 0, 0);
      // causal mask (the diagonal chunk only)
      if (c == jtmax) {
        const int k0 = c * 64;
#pragma unroll
        for (int ni = 0; ni < 4; ++ni) {
          const int col = k0 + ni * 16 + m;
#pragma unroll
          for (int r = 0; r < 4; ++r) {
            const int gr = r0 + rw * 16 + q * 4 + r;
            if (col > gr) s[ni][r] = -1e30f;
          }
        }
      }
      // scale to exp2 domain once; branch-free online rescale (max only)
#pragma unroll
      for (int ni = 0; ni < 4; ++ni)
#pragma unroll
        for (int r = 0; r < 4; ++r) s[ni][r] *= L2E;
#pragma unroll
      for (int r = 0; r < 4; ++r) {
        float tmx = fmaxf(fmaxf(s[0][r], s[1][r]), fmaxf(s[2][r], s[3][r]));
#pragma unroll
        for (int x = 1; x < 16; x <<= 1) tmx = fmaxf(tmx, __shfl_xor(tmx, x));
        const float nm = fmaxf(mrun[r], tmx);
        const float al = __builtin_amdgcn_exp2f(mrun[r] - nm);
        mrun[r] = nm;
        o5[r] *= al;
#pragma unroll
        for (int ni = 0; ni < 4; ++ni) o[ni][r] *= al;
      }
#pragma unroll
      for (int ni = 0; ni < 4; ++ni)
#pragma unroll
        for (int r = 0; r < 4; ++r) {
          const float pp = __builtin_amdgcn_exp2f(s[ni][r] - mrun[r]);
          wfrag(pw, q * 4 + r, ni * 16 + m, (f16)pp);
        }
      // PV: O += P . vc  ;  o5 += P . 1  (row sums — replaces shfl sum-reduce)
#pragma unroll
      for (int ks = 0; ks < 2; ++ks) {
        half8 af = rdfrag(pw, m, ks, q);
#pragma unroll
        for (int ni = 0; ni < 4; ++ni)
          o[ni] = __builtin_amdgcn_mfma_f32_16x16x32_f16(af, bV[ks][ni], o[ni], 0, 0, 0);
        o5 = __builtin_amdgcn_mfma_f32_16x16x32_f16(af, ones, o5, 0, 0, 0);
      }
    }
    __builtin_amdgcn_sched_barrier(0);
    __builtin_amdgcn_s_barrier();   // all reads of buf[p&1] done before overwrite
    // rotate prefetched C into place
#pragma unroll
    for (int ks = 0; ks < 2; ++ks)
#pragma unroll
      for (int ni = 0; ni < 4; ++ni) cC[ks][ni] = nC[ks][ni];
  }

  // drain dangling (garbage) staging before aliasing buf0 as merge scratch
  asm volatile("s_waitcnt vmcnt(0)" ::: "memory");
  __builtin_amdgcn_s_barrier();

  // 2-way merge across parity pairs: wave w+2 publishes partials, wave w combines.
  float* OB = (float*)L;
  float* MB = (float*)L + 2 * 16 * 68;
  float* LB = MB + 2 * 16;
  if (d == 1) {
#pragma unroll
    for (int ni = 0; ni < 4; ++ni)
#pragma unroll
      for (int r = 0; r < 4; ++r)
        OB[(rw * 16 + q * 4 + r) * 68 + ni * 16 + m] = o[ni][r];
    if (m == 0)
#pragma unroll
      for (int r = 0; r < 4; ++r) {
        MB[rw * 16 + q * 4 + r] = mrun[r];
        LB[rw * 16 + q * 4 + r] = o5[r];
      }
  }
  __syncthreads();
  if (d == 0) {
#pragma unroll
    for (int r = 0; r < 4; ++r) {
      const int row = q * 4 + r;
      const float m2 = MB[rw * 16 + row], l2 = LB[rw * 16 + row];
      const float ms = fmaxf(mrun[r], m2);
      const float e1 = __builtin_amdgcn_exp2f(mrun[r] - ms);
      const float e2 = __builtin_amdgcn_exp2f(m2 - ms);
      const float inv = __builtin_amdgcn_rcpf(o5[r] * e1 + l2 * e2);
      const int gr = r0 + rw * 16 + row;
#pragma unroll
      for (int ni = 0; ni < 4; ++ni) {
        const float ov = o[ni][r] * e1 + OB[(rw * 16 + row) * 68 + ni * 16 + m] * e2;
        Oh[(size_t)gr * (H * DH) + h * DH + ni * 16 + m] = (f16)(ov * inv);
      }
    }
  }
}

// out = O @ w_out^T, fp32 result.
__global__ __launch_bounds__(256) void k_out(const f16* __restrict__ Oh, const f16* __restrict__ wo,
                                             float* __restrict__ out) {
  __shared__ __align__(16) f16 lds[128 * LDSH];
  f16* As = lds; f16* Bs = lds + 128 * 64;
  const int tid = threadIdx.x, w = tid >> 6, l = tid & 63;
  const int tm = blockIdx.x * 128, tn = blockIdx.y * 128;
  const int wm = (w >> 1) * 64, wn = (w & 1) * 64;
  float4v acc[4][4] = {};
  for (int k0 = 0; k0 < DIM; k0 += 64) {
    stage64<128, 256>(Oh + (size_t)tm * DIM + k0, DIM, As, tid);
    stage64<128, 256>(wo + (size_t)tn * DIM + k0, DIM, Bs, tid);
    __syncthreads();
    gemm64(As, Bs, wm, wn, l, acc);
    __syncthreads();
  }
  const int rbase = (l >> 4) * 4, cidx = l & 15;
#pragma unroll
  for (int mi = 0; mi < 4; ++mi)
#pragma unroll
    for (int ni = 0; ni < 4; ++ni)
#pragma unroll
      for (int r = 0; r < 4; ++r) {
        const int n = tm + wm + mi * 16 + rbase + r;
        const int dmo = tn + wn + ni * 16 + cidx;
        out[(size_t)n * DIM + dmo] = acc[mi][ni][r];
      }
}

extern "C" void kernel_launch(void* const* d_in, const int* in_sizes, int n_in,
                              void* d_out, int out_size, void* d_ws, size_t ws_size,
                              hipStream_t stream) {
  const float* x = (const float*)d_in[0];
  const float* wqkv = (const float*)d_in[1];
  const float* wout = (const float*)d_in[2];
  float* out = (float*)d_out;
  char* ws = (char*)d_ws;

  size_t off = 0;
  auto alloc = [&](size_t b) { size_t o = off; off += (b + 255) & ~(size_t)255; return o; };
  f16* xh  = (f16*)(ws + alloc((size_t)N * DIM * 2));
  f16* wqh = (f16*)(ws + alloc((size_t)F6 * DIM * 2));
  f16* woh = (f16*)(ws + alloc((size_t)DIM * H * DH * 2));
  f16* quh = (f16*)(ws + alloc((size_t)H * N * DH * 2));
  f16* kuh = (f16*)(ws + alloc((size_t)H * N * DH * 2));
  f16* vuh = (f16*)(ws + alloc((size_t)H * N * DH * 2));
  f16* qch = (f16*)(ws + alloc((size_t)H * N * DH * 2));
  f16* kch = (f16*)(ws + alloc((size_t)H * N * DH * 2));
  f16* vcT = (f16*)(ws + alloc((size_t)H * DH * N * 2));
  f16* vuT = (f16*)(ws + alloc((size_t)H * DH * N * 2));
  f16* Oh  = (f16*)(ws + alloc((size_t)N * H * DH * 2));
  const size_t persist = off;

  // per head: sig tiles + D/C + diag tiles (scob eliminated by k_favs fusion)
  const size_t per_head = ((size_t)NTILES * TS + (size_t)16 * KD + (size_t)16 * TS) * 2;
  int G = (ws_size > persist + 4096) ? (int)((ws_size - persist - 4096) / per_head) : 1;
  if (G < 1) G = 1;
  if (G > 16) G = 16;
  {  // normalize so rounds are evenly sized (prefer G=8 for head->XCD pinning)
    const int R = (H + G - 1) / G;
    G = (H + R - 1) / R;
  }
  f16* sigb  = (f16*)(ws + alloc((size_t)G * NTILES * TS * 2));
  f16* DC    = (f16*)(ws + alloc((size_t)G * 16 * KD * 2));
  f16* diagb = (f16*)(ws + alloc((size_t)G * 16 * TS * 2));

  k_cast<<<(N * DIM / 4 + 255) / 256, 256, 0, stream>>>(x, xh, N * DIM / 4);
  k_cast<<<(F6 * DIM / 4 + 255) / 256, 256, 0, stream>>>(wqkv, wqh, F6 * DIM / 4);
  k_cast<<<(DIM * H * DH / 4 + 255) / 256, 256, 0, stream>>>(wout, woh, DIM * H * DH / 4);

  k_qkv<<<dim3(N / 128, F6 / 128), 256, 0, stream>>>(xh, wqh, quh, kuh, vuh, qch, kch, vcT, vuT);

  for (int h0 = 0; h0 < H; h0 += G) {
    const int Gr = (H - h0 < G) ? (H - h0) : G;
    k_dsig<<<dim3(Gr, 136), 256, 0, stream>>>(quh, kuh, qch, vuh, vuT, sigb, DC, diagb, h0);
    k_scan<<<(Gr * KD + 255) / 256, 256, 0, stream>>>(DC, Gr * KD);
    k_favs<<<dim3(Gr, 64), 256, 0, stream>>>(qch, kch, DC, sigb, diagb, vcT, Oh, h0);
  }

  k_out<<<dim3(16, 8), 256, 0, stream>>>(Oh, woh, out);
}